// Round 11
// baseline (1582.644 us; speedup 1.0000x reference)
//
#include <hip/hip_runtime.h>
#include <hip/hip_bf16.h>

using u16 = unsigned short;
typedef __attribute__((ext_vector_type(8))) short bf16x8;
typedef __attribute__((ext_vector_type(4))) float f32x4;
typedef __attribute__((ext_vector_type(4))) u16 u16x4;

// Sizes (fixed): B=32, T=32, S=400, H=1024, I=1024

__device__ __forceinline__ float bf2f(u16 u){ union{unsigned int i; float f;} v; v.i = ((unsigned int)u)<<16; return v.f; }
__device__ __forceinline__ u16 f2bf(float f){ __hip_bfloat16 h = __float2bfloat16(f); return *reinterpret_cast<u16*>(&h); }
struct HL { u16 h, l; };
__device__ __forceinline__ HL split1(float f){
  HL r; r.h = f2bf(f); r.l = f2bf(f - bf2f(r.h)); return r;
}
__device__ __forceinline__ f32x4 mfma16(bf16x8 a, bf16x8 b, f32x4 c){ return __builtin_amdgcn_mfma_f32_16x16x32_bf16(a,b,c,0,0,0); }

// ---------------- merged cast / init kernel (runs once per launch) ----------------
// block ranges: [0,8192) wih | [8192,12288) whh | [12288,14336) wout
//               [14336,15360) x | [15360,15795) misc | [15795,22195) encb
__global__ __launch_bounds__(256) void cast_all_k(
    const float* __restrict__ Wih, const float* __restrict__ Whh,
    const float* __restrict__ Wout_f, const float* __restrict__ inp,
    const float* __restrict__ h0, const float* __restrict__ c0,
    const float* __restrict__ ha0, const float* __restrict__ past,
    const float* __restrict__ enc,
    u16* __restrict__ Wxh, u16* __restrict__ Wxl, u16* __restrict__ Wrh, u16* __restrict__ Wrl,
    u16* __restrict__ Woh, u16* __restrict__ Wol,
    u16* __restrict__ Xh, u16* __restrict__ Xl,
    u16* __restrict__ Zh0, u16* __restrict__ Zl0, float* __restrict__ cbuf,
    float* __restrict__ out_past, float* __restrict__ out_loss,
    u16* __restrict__ encb, int do_encb)
{
  const int blk = blockIdx.x;
  if (blk < 8192){
    int v = blk*256 + threadIdx.x;
    int flat = v*4; int j = flat >> 11; int k = flat & 2047;
    float4 f = *(const float4*)(Wih + flat);
    HL s0 = split1(f.x), s1 = split1(f.y), s2 = split1(f.z), s3 = split1(f.w);
    u16x4 h, l;
    h[0]=s0.h; h[1]=s1.h; h[2]=s2.h; h[3]=s3.h;
    l[0]=s0.l; l[1]=s1.l; l[2]=s2.l; l[3]=s3.l;
    if (k < 1024){
      *(u16x4*)(Wxh + (size_t)j*1024 + k) = h;
      *(u16x4*)(Wxl + (size_t)j*1024 + k) = l;
    } else {
      *(u16x4*)(Wrh + (size_t)j*2048 + (k-1024)) = h;
      *(u16x4*)(Wrl + (size_t)j*2048 + (k-1024)) = l;
    }
  } else if (blk < 12288){
    int v = (blk-8192)*256 + threadIdx.x;
    int flat = v*4; int j = flat >> 10; int k = flat & 1023;
    float4 f = *(const float4*)(Whh + flat);
    HL s0 = split1(f.x), s1 = split1(f.y), s2 = split1(f.z), s3 = split1(f.w);
    u16x4 h, l;
    h[0]=s0.h; h[1]=s1.h; h[2]=s2.h; h[3]=s3.h;
    l[0]=s0.l; l[1]=s1.l; l[2]=s2.l; l[3]=s3.l;
    *(u16x4*)(Wrh + (size_t)j*2048 + 1024 + k) = h;
    *(u16x4*)(Wrl + (size_t)j*2048 + 1024 + k) = l;
  } else if (blk < 14336){
    int v = (blk-12288)*256 + threadIdx.x;
    float4 f = *(const float4*)(Wout_f + (size_t)v*4);
    HL s0 = split1(f.x), s1 = split1(f.y), s2 = split1(f.z), s3 = split1(f.w);
    u16x4 h, l;
    h[0]=s0.h; h[1]=s1.h; h[2]=s2.h; h[3]=s3.h;
    l[0]=s0.l; l[1]=s1.l; l[2]=s2.l; l[3]=s3.l;
    *(u16x4*)(Woh + (size_t)v*4) = h;
    *(u16x4*)(Wol + (size_t)v*4) = l;
  } else if (blk < 15360){
    int v = (blk-14336)*256 + threadIdx.x;
    int flat = v*4; int m = flat >> 10; int k = flat & 1023;
    int t = m >> 5, b = m & 31;
    float4 f = *(const float4*)(inp + ((size_t)(b*32 + t) << 10) + k);
    HL s0 = split1(f.x), s1 = split1(f.y), s2 = split1(f.z), s3 = split1(f.w);
    u16x4 h, l;
    h[0]=s0.h; h[1]=s1.h; h[2]=s2.h; h[3]=s3.h;
    l[0]=s0.l; l[1]=s1.l; l[2]=s2.l; l[3]=s3.l;
    *(u16x4*)(Xh + flat) = h;
    *(u16x4*)(Xl + flat) = l;
  } else if (blk < 15795){
    int idx = (blk-15360)*256 + threadIdx.x;
    if (idx < 65536){
      int b = idx >> 11, col = idx & 2047;
      float v = (col < 1024) ? ha0[b*1024 + col] : h0[b*1024 + col - 1024];
      HL s = split1(v);
      Zh0[idx] = s.h; Zl0[idx] = s.l;
    } else if (idx < 65536 + 32768){
      int i = idx - 65536; cbuf[i] = c0[i];
    } else if (idx < 65536 + 32768 + 12800){
      int i = idx - 98304; out_past[i] = past[i];
    } else if (idx == 65536 + 32768 + 12800){
      out_loss[0] = 0.f;
    }
  } else {
    if (!do_encb) return;
    int v = (blk-15795)*256 + threadIdx.x;
    size_t flat = (size_t)v*8;
    int c = flat & 1023; int rem = flat >> 10;   // rem = s*32 + b
    int b = rem & 31, s = rem >> 5;
    float4 f0 = *(const float4*)(enc + flat);
    float4 f1 = *(const float4*)(enc + flat + 4);
    u16x4 h0v, h1v;
    h0v[0]=f2bf(f0.x); h0v[1]=f2bf(f0.y); h0v[2]=f2bf(f0.z); h0v[3]=f2bf(f0.w);
    h1v[0]=f2bf(f1.x); h1v[1]=f2bf(f1.y); h1v[2]=f2bf(f1.z); h1v[3]=f2bf(f1.w);
    u16* dst = encb + ((size_t)b*400 + s)*1024 + c;
    *(u16x4*)dst = h0v;
    *(u16x4*)(dst+4) = h1v;
  }
}

// W_attn [g][c] -> WaT [c][g] split hi/lo
__global__ __launch_bounds__(256) void watsplit_k(const float* __restrict__ Wattn,
    u16* __restrict__ Wth, u16* __restrict__ Wtl){
  __shared__ float t[32][33];
  int gx = blockIdx.x, cx = blockIdx.y;
  int ty = threadIdx.x >> 5, tx = threadIdx.x & 31;
  #pragma unroll
  for (int i=0;i<4;++i){
    int g = gx*32 + ty + i*8;
    t[ty+i*8][tx] = Wattn[(size_t)g*1024 + cx*32 + tx];
  }
  __syncthreads();
  #pragma unroll
  for (int i=0;i<4;++i){
    int c = cx*32 + ty + i*8;
    HL s = split1(t[tx][ty+i*8]);
    Wth[(size_t)c*1024 + gx*32 + tx] = s.h;
    Wtl[(size_t)c*1024 + gx*32 + tx] = s.l;
  }
}

// ---------------- 128x128 split-precision MFMA GEMM (x-path precompute) ----------------
__global__ __launch_bounds__(256) void gemm128_bias_k(
    const u16* __restrict__ Ah, const u16* __restrict__ Al,
    const u16* __restrict__ Bh, const u16* __restrict__ Bl, float* __restrict__ C,
    const float* __restrict__ bias0, const float* __restrict__ bias1, int M, int N, int K)
{
  __shared__ __align__(16) u16 Ash[4096], Asl[4096], Bsh[4096], Bsl[4096];
  const int tid = threadIdx.x;
  const int lane = tid & 63, w = tid >> 6;
  const int wm = w >> 1, wn = w & 1;
  const int m0 = blockIdx.y * 128, n0 = blockIdx.x * 128;
  const int r = lane & 15, q = lane >> 4;

  f32x4 acc[4][4];
  #pragma unroll
  for (int i=0;i<4;i++)
    #pragma unroll
    for (int j=0;j<4;j++) acc[i][j] = (f32x4){0.f,0.f,0.f,0.f};

  const int NT = K >> 5;
  const int srow = tid >> 2;
  const int skp  = (tid & 3) * 8;
  bf16x8 rah0, rah1, ral0, ral1, rbh0, rbh1, rbl0, rbl1;

  {
    size_t ao = (size_t)(m0 + srow) * K + skp;
    size_t bo = (size_t)(n0 + srow) * K + skp;
    rah0 = *(const bf16x8*)(Ah + ao);  rah1 = *(const bf16x8*)(Ah + ao + (size_t)64*K);
    ral0 = *(const bf16x8*)(Al + ao);  ral1 = *(const bf16x8*)(Al + ao + (size_t)64*K);
    rbh0 = *(const bf16x8*)(Bh + bo);  rbh1 = *(const bf16x8*)(Bh + bo + (size_t)64*K);
    rbl0 = *(const bf16x8*)(Bl + bo);  rbl1 = *(const bf16x8*)(Bl + bo + (size_t)64*K);
  }

  for (int kt = 0; kt < NT; ++kt){
    __syncthreads();
    *(bf16x8*)(Ash + tid*8)        = rah0;
    *(bf16x8*)(Ash + 2048 + tid*8) = rah1;
    *(bf16x8*)(Asl + tid*8)        = ral0;
    *(bf16x8*)(Asl + 2048 + tid*8) = ral1;
    *(bf16x8*)(Bsh + tid*8)        = rbh0;
    *(bf16x8*)(Bsh + 2048 + tid*8) = rbh1;
    *(bf16x8*)(Bsl + tid*8)        = rbl0;
    *(bf16x8*)(Bsl + 2048 + tid*8) = rbl1;
    __syncthreads();
    if (kt + 1 < NT){
      size_t ao = (size_t)(m0 + srow) * K + (kt+1)*32 + skp;
      size_t bo = (size_t)(n0 + srow) * K + (kt+1)*32 + skp;
      rah0 = *(const bf16x8*)(Ah + ao);  rah1 = *(const bf16x8*)(Ah + ao + (size_t)64*K);
      ral0 = *(const bf16x8*)(Al + ao);  ral1 = *(const bf16x8*)(Al + ao + (size_t)64*K);
      rbh0 = *(const bf16x8*)(Bh + bo);  rbh1 = *(const bf16x8*)(Bh + bo + (size_t)64*K);
      rbl0 = *(const bf16x8*)(Bl + bo);  rbl1 = *(const bf16x8*)(Bl + bo + (size_t)64*K);
    }
    bf16x8 afh[4], afl[4], bfh[4], bfl[4];
    #pragma unroll
    for (int mf=0; mf<4; ++mf){
      int off = (wm*64 + mf*16 + r)*32 + q*8;
      afh[mf] = *(const bf16x8*)(Ash + off);
      afl[mf] = *(const bf16x8*)(Asl + off);
    }
    #pragma unroll
    for (int nf=0; nf<4; ++nf){
      int off = (wn*64 + nf*16 + r)*32 + q*8;
      bfh[nf] = *(const bf16x8*)(Bsh + off);
      bfl[nf] = *(const bf16x8*)(Bsl + off);
    }
    #pragma unroll
    for (int mf=0; mf<4; ++mf)
      #pragma unroll
      for (int nf=0; nf<4; ++nf){
        acc[mf][nf] = mfma16(afh[mf], bfh[nf], acc[mf][nf]);
        acc[mf][nf] = mfma16(afh[mf], bfl[nf], acc[mf][nf]);
        acc[mf][nf] = mfma16(afl[mf], bfh[nf], acc[mf][nf]);
      }
  }

  #pragma unroll
  for (int mf=0; mf<4; ++mf)
    #pragma unroll
    for (int nf=0; nf<4; ++nf)
      #pragma unroll
      for (int rr=0; rr<4; ++rr){
        int row = m0 + wm*64 + mf*16 + q*4 + rr;
        int col = n0 + wn*64 + nf*16 + r;
        C[(size_t)row*N + col] = acc[mf][nf][rr] + bias0[col] + bias1[col];
      }
}

// ---------------- per-step kernels (5 dispatches, no cross-block sync) ----------------

// Fused recurrent GEMM + LSTM cell, single dispatch, full-K per block.
// 512 blocks (2/CU): block j2 computes cols j2*2..+1 of ALL FOUR gates.
// Fragment row r -> gate (r>>2), col (r&1); rows r and r|2 are duplicates (ignored).
__global__ __launch_bounds__(512, 4) void rec_cell_k(
    const u16* __restrict__ Zh, const u16* __restrict__ Zl,
    const u16* __restrict__ Wh, const u16* __restrict__ Wl,
    const float* __restrict__ gX, float* __restrict__ cbuf,
    u16* __restrict__ Znh, u16* __restrict__ Znl,
    u16* __restrict__ Zoh, u16* __restrict__ Zol,
    float* __restrict__ out_h, float* __restrict__ out_c, int last)
{
  __shared__ float red[8][512];
  __shared__ float gsum[512];
  const int tid = threadIdx.x, lane = tid & 63, w = tid >> 6;
  const int j2 = blockIdx.x;           // 0..511
  const int r = lane & 15, q = lane >> 4;
  const int k0 = w*256;

  f32x4 acc0 = (f32x4){0,0,0,0}, acc1 = (f32x4){0,0,0,0};
  const size_t aoff = (size_t)r*2048 + k0 + q*8;
  const size_t boff = (size_t)((r>>2)*1024 + j2*2 + (r&1))*2048 + k0 + q*8;
  #pragma unroll
  for (int kt = 0; kt < 8; ++kt){
    bf16x8 a0h = *(const bf16x8*)(Zh + aoff + kt*32);
    bf16x8 a0l = *(const bf16x8*)(Zl + aoff + kt*32);
    bf16x8 a1h = *(const bf16x8*)(Zh + aoff + (size_t)16*2048 + kt*32);
    bf16x8 a1l = *(const bf16x8*)(Zl + aoff + (size_t)16*2048 + kt*32);
    bf16x8 bh  = *(const bf16x8*)(Wh + boff + kt*32);
    bf16x8 bl  = *(const bf16x8*)(Wl + boff + kt*32);
    acc0 = mfma16(a0h, bh, acc0);
    acc0 = mfma16(a0h, bl, acc0);
    acc0 = mfma16(a0l, bh, acc0);
    acc1 = mfma16(a1h, bh, acc1);
    acc1 = mfma16(a1h, bl, acc1);
    acc1 = mfma16(a1l, bh, acc1);
  }
  #pragma unroll
  for (int rr=0; rr<4; ++rr){
    red[w][(q*4+rr)*16 + r]        = acc0[rr];   // b 0..15
    red[w][256 + (q*4+rr)*16 + r]  = acc1[rr];   // b 16..31
  }
  __syncthreads();
  {
    float v = 0.f;
    #pragma unroll
    for (int w2=0; w2<8; ++w2) v += red[w2][tid];
    gsum[tid] = v;   // gsum[b*16 + fragment_col]
  }
  __syncthreads();
  if (tid < 64){
    int b = tid >> 1, c = tid & 1;
    int j = j2*2 + c;
    float gs[4];
    #pragma unroll
    for (int g=0; g<4; ++g)
      gs[g] = gsum[b*16 + g*4 + c] + gX[(size_t)b*4096 + g*1024 + j];
    int idx = b*1024 + j;
    float iv = 1.f/(1.f + expf(-gs[0]));
    float fv = 1.f/(1.f + expf(-gs[1]));
    float gv = tanhf(gs[2]);
    float ov = 1.f/(1.f + expf(-gs[3]));
    float cn = fv * cbuf[idx] + iv*gv;
    cbuf[idx] = cn;
    float h = ov * tanhf(cn);
    HL s = split1(h);
    size_t zi = (size_t)b*2048 + 1024 + j;
    Znh[zi] = s.h; Znl[zi] = s.l;
    Zoh[zi] = s.h; Zol[zi] = s.l;
    if (last){ out_h[idx] = h; out_c[idx] = cn; }
  }
}

// u[b,c] = sum_g h[b,g] * W_attn[g,c] via split MFMA vs transposed WaT.
// 128 blocks = (64 cc) x (2 b-halves).
__global__ __launch_bounds__(512) void u_mfma_k(
    const u16* __restrict__ Zoh, const u16* __restrict__ Zol,
    const u16* __restrict__ Wth, const u16* __restrict__ Wtl,
    float* __restrict__ ubuf)
{
  __shared__ float red[8][256];
  const int tid = threadIdx.x, lane = tid & 63, w = tid >> 6;
  const int cc = blockIdx.x & 63, bh = blockIdx.x >> 6;
  const int r = lane & 15, q = lane >> 4;
  f32x4 acc0 = (f32x4){0,0,0,0};
  const size_t aoff = (size_t)(bh*16 + r)*2048 + 1024 + w*128 + q*8;
  const size_t boff = (size_t)(cc*16 + r)*1024 + w*128 + q*8;
  #pragma unroll
  for (int kt=0; kt<4; ++kt){
    bf16x8 ah = *(const bf16x8*)(Zoh + aoff + kt*32);
    bf16x8 al = *(const bf16x8*)(Zol + aoff + kt*32);
    bf16x8 bh_ = *(const bf16x8*)(Wth + boff + kt*32);
    bf16x8 bl_ = *(const bf16x8*)(Wtl + boff + kt*32);
    acc0 = mfma16(ah, bh_, acc0);
    acc0 = mfma16(ah, bl_, acc0);
    acc0 = mfma16(al, bh_, acc0);
  }
  #pragma unroll
  for (int rr=0; rr<4; ++rr)
    red[w][(q*4+rr)*16 + r] = acc0[rr];
  __syncthreads();
  if (tid < 256){
    int bloc = tid >> 4, jj = tid & 15;
    float v = 0.f;
    #pragma unroll
    for (int w2=0; w2<8; ++w2) v += red[w2][tid];
    ubuf[(size_t)(bh*16 + bloc)*1024 + cc*16 + jj] = v;
  }
}

// Flash attention pass, bf16 enc, two-phase (scores then accumulate):
// 512 blocks = (32 b x 16 s-chunks of 25), __launch_bounds__ forces 2 blocks/CU.
__global__ __launch_bounds__(512, 4) void flash_bf16_k(const u16* __restrict__ encb,
    const float* __restrict__ ubuf, float* __restrict__ scbuf,
    float* __restrict__ ctxp, float* __restrict__ mlbuf)
{
  __shared__ float wacc[8][1024];
  __shared__ float wml[16];
  const int tid = threadIdx.x, lane = tid & 63, w = tid >> 6;
  const int b = blockIdx.x >> 4, sc16 = blockIdx.x & 15;
  const int s0 = sc16 * 25;

  const float* up = ubuf + (size_t)b*1024 + lane*16;
  float uu[16];
  #pragma unroll
  for (int i=0;i<4;i++){ float4 t4 = *(const float4*)(up + i*4); uu[4*i]=t4.x; uu[4*i+1]=t4.y; uu[4*i+2]=t4.z; uu[4*i+3]=t4.w; }

  const int nr = (w == 0) ? 4 : 3;   // 25 rows over 8 waves, stride 8
  bf16x8 e0[4], e1[4];
  #pragma unroll
  for (int i=0;i<4;++i){
    if (i < nr){
      const u16* ep = encb + ((size_t)b*400 + s0 + w + 8*i)*1024 + lane*16;
      e0[i] = *(const bf16x8*)ep;
      e1[i] = *(const bf16x8*)(ep + 8);
    }
  }
  float scv[4];
  #pragma unroll
  for (int i=0;i<4;++i){
    if (i < nr){
      float sc = 0.f;
      #pragma unroll
      for (int j=0;j<8;j++) sc = fmaf(bf2f((u16)e0[i][j]), uu[j], sc);
      #pragma unroll
      for (int j=0;j<8;j++) sc = fmaf(bf2f((u16)e1[i][j]), uu[8+j], sc);
      scv[i] = sc;
    } else scv[i] = -1e30f;
  }
  #pragma unroll
  for (int off=32; off; off>>=1){
    #pragma unroll
    for (int i=0;i<4;++i) scv[i] += (i < nr) ? __shfl_xor(scv[i], off) : 0.f;
  }
  #pragma unroll
  for (int i=0;i<4;++i)
    if (i < nr && lane == 0) scbuf[(size_t)b*400 + s0 + w + 8*i] = scv[i];

  float m = scv[0];
  #pragma unroll
  for (int i=1;i<4;++i) if (i < nr) m = fmaxf(m, scv[i]);
  float wt[4]; float l = 0.f;
  #pragma unroll
  for (int i=0;i<4;++i){
    wt[i] = (i < nr) ? expf(scv[i] - m) : 0.f;
    l += wt[i];
  }
  float acc[16];
  #pragma unroll
  for (int j=0;j<16;j++) acc[j] = 0.f;
  #pragma unroll
  for (int i=0;i<4;++i){
    if (i < nr){
      #pragma unroll
      for (int j=0;j<8;j++)  acc[j]   = fmaf(wt[i], bf2f((u16)e0[i][j]), acc[j]);
      #pragma unroll
      for (int j=0;j<8;j++)  acc[8+j] = fmaf(wt[i], bf2f((u16)e1[i][j]), acc[8+j]);
    }
  }

  #pragma unroll
  for (int j=0;j<16;j++) wacc[w][lane*16+j] = acc[j];
  if (lane == 0){ wml[w*2] = m; wml[w*2+1] = l; }
  __syncthreads();

  float M = wml[0];
  #pragma unroll
  for (int i=1;i<8;i++) M = fmaxf(M, wml[i*2]);
  float c0v = 0.f, c1v = 0.f;
  #pragma unroll
  for (int i=0;i<8;i++){
    float f = expf(wml[i*2] - M);
    c0v = fmaf(wacc[i][tid],       f, c0v);
    c1v = fmaf(wacc[i][tid + 512], f, c1v);
  }
  size_t co = ((size_t)b*16 + sc16)*1024;
  ctxp[co + tid]       = c0v;
  ctxp[co + tid + 512] = c1v;
  if (tid == 0){
    float L = 0.f;
    #pragma unroll
    for (int i=0;i<8;i++) L += wml[i*2+1] * expf(wml[i*2] - M);
    mlbuf[((size_t)b*16 + sc16)*2]     = M;
    mlbuf[((size_t)b*16 + sc16)*2 + 1] = L;
  }
}

// Flash attention pass, f32 enc fallback, same two-phase structure.
__global__ __launch_bounds__(512, 4) void flash_f32_k(const float* __restrict__ enc,
    const float* __restrict__ ubuf, float* __restrict__ scbuf,
    float* __restrict__ ctxp, float* __restrict__ mlbuf)
{
  __shared__ float wacc[8][1024];
  __shared__ float wml[16];
  const int tid = threadIdx.x, lane = tid & 63, w = tid >> 6;
  const int b = blockIdx.x >> 4, sc16 = blockIdx.x & 15;
  const int s0 = sc16 * 25;

  const float* up = ubuf + (size_t)b*1024 + lane*16;
  float uu[16];
  #pragma unroll
  for (int i=0;i<4;i++){ float4 t4 = *(const float4*)(up + i*4); uu[4*i]=t4.x; uu[4*i+1]=t4.y; uu[4*i+2]=t4.z; uu[4*i+3]=t4.w; }

  const int nr = (w == 0) ? 4 : 3;
  float er[4][16];
  #pragma unroll
  for (int i=0;i<4;++i){
    if (i < nr){
      const float* ep = enc + ((size_t)(s0 + w + 8*i)*32 + b)*1024 + lane*16;
      #pragma unroll
      for (int jj=0;jj<4;jj++){
        float4 e4 = *(const float4*)(ep + jj*4);
        er[i][4*jj]=e4.x; er[i][4*jj+1]=e4.y; er[i][4*jj+2]=e4.z; er[i][4*jj+3]=e4.w;
      }
    }
  }
  float scv[4];
  #pragma unroll
  for (int i=0;i<4;++i){
    if (i < nr){
      float sc = 0.f;
      #pragma unroll
      for (int j=0;j<16;j++) sc = fmaf(er[i][j], uu[j], sc);
      scv[i] = sc;
    } else scv[i] = -1e30f;
  }
  #pragma unroll
  for (int off=32; off; off>>=1){
    #pragma unroll
    for (int i=0;i<4;++i) scv[i] += (i < nr) ? __shfl_xor(scv[i], off) : 0.f;
  }
  #pragma unroll
  for (int i=0;i<4;++i)
    if (i < nr && lane == 0) scbuf[(size_t)b*400 + s0 + w + 8*i] = scv[i];

  float m = scv[0];
  #pragma unroll
  for (int i=1;i<4;++i) if (i < nr) m = fmaxf(m, scv[i]);
  float wt[4]; float l = 0.f;
  #pragma unroll
  for (int i=0;i<4;++i){
    wt[i] = (i < nr) ? expf(scv[i] - m) : 0.f;
    l += wt[i];
  }
  float acc[16];
  #pragma unroll
  for (int j=0;j<16;j++) acc[j] = 0.f;
  #pragma unroll
  for (int i=0;i<4;++i){
    if (i < nr){
      #pragma unroll
      for (int j=0;j<16;j++) acc[j] = fmaf(wt[i], er[i][j], acc[j]);
    }
  }

  #pragma unroll
  for (int j=0;j<16;j++) wacc[w][lane*16+j] = acc[j];
  if (lane == 0){ wml[w*2] = m; wml[w*2+1] = l; }
  __syncthreads();

  float M = wml[0];
  #pragma unroll
  for (int i=1;i<8;i++) M = fmaxf(M, wml[i*2]);
  float c0v = 0.f, c1v = 0.f;
  #pragma unroll
  for (int i=0;i<8;i++){
    float f = expf(wml[i*2] - M);
    c0v = fmaf(wacc[i][tid],       f, c0v);
    c1v = fmaf(wacc[i][tid + 512], f, c1v);
  }
  size_t co = ((size_t)b*16 + sc16)*1024;
  ctxp[co + tid]       = c0v;
  ctxp[co + tid + 512] = c1v;
  if (tid == 0){
    float L = 0.f;
    #pragma unroll
    for (int i=0;i<8;i++) L += wml[i*2+1] * expf(wml[i*2] - M);
    mlbuf[((size_t)b*16 + sc16)*2]     = M;
    mlbuf[((size_t)b*16 + sc16)*2 + 1] = L;
  }
}

// Combine 16 chunk partials: global (M,L), ctx -> Z split, attn output row.
__global__ __launch_bounds__(256) void combine_k(const float* __restrict__ scbuf,
    const float* __restrict__ ctxp, const float* __restrict__ mlbuf,
    u16* __restrict__ Zoh, u16* __restrict__ Zol, float* __restrict__ attn_out)
{
  const int b = blockIdx.x >> 3, cc = blockIdx.x & 7;
  const int tid = threadIdx.x;
  float M = -1e30f;
  #pragma unroll
  for (int i=0;i<16;i++) M = fmaxf(M, mlbuf[((size_t)b*16 + i)*2]);
  float L = 0.f;
  #pragma unroll
  for (int i=0;i<16;i++) L += mlbuf[((size_t)b*16 + i)*2 + 1] * expf(mlbuf[((size_t)b*16 + i)*2] - M);
  float invL = 1.f / L;
  if (tid < 128){
    int col = cc*128 + tid;
    float v = 0.f;
    #pragma unroll
    for (int i=0;i<16;i++)
      v = fmaf(ctxp[((size_t)b*16 + i)*1024 + col], expf(mlbuf[((size_t)b*16 + i)*2] - M), v);
    HL s = split1(v * invL);
    size_t zi = (size_t)b*2048 + col;
    Zoh[zi] = s.h; Zol[zi] = s.l;
  } else if (tid < 128 + 50){
    int s = cc*50 + (tid - 128);
    attn_out[(size_t)b*400 + s] = expf(scbuf[(size_t)b*400 + s] - M) * invL;
  }
}

// Fused full-K out-GEMM + tanh, single dispatch, no partial buffers.
// 128 blocks = (64 ub col-groups) x (2 bh row-halves); 8 waves K-split (256 each).
__global__ __launch_bounds__(512) void outg_fused_k(
    const u16* __restrict__ Zoh, const u16* __restrict__ Zol,
    const u16* __restrict__ Woh, const u16* __restrict__ Wol,
    float* __restrict__ out_outp /* + t*1024 */, u16* __restrict__ Znh, u16* __restrict__ Znl,
    float* __restrict__ out_hattn, int last)
{
  __shared__ float red[8][256];
  const int tid = threadIdx.x, lane = tid & 63, w = tid >> 6;
  const int ub = blockIdx.x & 63, bh = blockIdx.x >> 6;
  const int r = lane & 15, q = lane >> 4;
  const int k0 = w*256;
  f32x4 acc0 = (f32x4){0,0,0,0};
  const size_t aoff = (size_t)(bh*16 + r)*2048 + k0 + q*8;
  const size_t boff = (size_t)(ub*16 + r)*2048 + k0 + q*8;
  #pragma unroll
  for (int kt=0; kt<8; ++kt){
    bf16x8 ah = *(const bf16x8*)(Zoh + aoff + kt*32);
    bf16x8 al = *(const bf16x8*)(Zol + aoff + kt*32);
    bf16x8 bh_ = *(const bf16x8*)(Woh + boff + kt*32);
    bf16x8 bl_ = *(const bf16x8*)(Wol + boff + kt*32);
    acc0 = mfma16(ah, bh_, acc0);
    acc0 = mfma16(ah, bl_, acc0);
    acc0 = mfma16(al, bh_, acc0);
  }
  #pragma unroll
  for (int rr=0; rr<4; ++rr)
    red[w][(q*4+rr)*16 + r] = acc0[rr];
  __syncthreads();
  if (tid < 256){
    int bloc = tid >> 4, jj = tid & 15;
    float z = 0.f;
    #pragma unroll
    for (int w2=0; w2<8; ++w2) z += red[w2][tid];
    int b = bh*16 + bloc;
    int u = ub*16 + jj;
    float ha = tanhf(z);
    out_outp[(size_t)b*32768 + u] = ha;
    HL s = split1(ha);
    Znh[(size_t)b*2048 + u] = s.h;
    Znl[(size_t)b*2048 + u] = s.l;
    if (last) out_hattn[(size_t)b*1024 + u] = ha;
  }
}

// ---------------- launch ----------------

extern "C" void kernel_launch(void* const* d_in, const int* in_sizes, int n_in,
                              void* d_out, int out_size, void* d_ws, size_t ws_size,
                              hipStream_t stream)
{
  const float* input_ = (const float*)d_in[0];
  const float* h0     = (const float*)d_in[1];
  const float* c0     = (const float*)d_in[2];
  const float* ha0    = (const float*)d_in[3];
  const float* enc    = (const float*)d_in[4];
  const float* past   = (const float*)d_in[5];
  const float* W_ih   = (const float*)d_in[6];
  const float* W_hh   = (const float*)d_in[7];
  const float* b_ih   = (const float*)d_in[8];
  const float* b_hh   = (const float*)d_in[9];
  const float* W_attn = (const float*)d_in[10];
  const float* W_out  = (const float*)d_in[11];
  float* out = (float*)d_out;

  // d_out layout (floats)
  const size_t OUT_OUTPUT = 0;            // [32][32][1024]
  const size_t OUT_H      = 1048576;
  const size_t OUT_C      = 1081344;
  const size_t OUT_HATTN  = 1114112;
  const size_t OUT_ATTN   = 1146880;      // [32][32][400]
  const size_t OUT_PAST   = 1556480;
  const size_t OUT_LOSS   = 1569280;

  // workspace layout (bytes)
  const size_t OFF_WRH   = 0;             // bf16 [4096][2048] hi
  const size_t OFF_WRL   = 16777216;
  const size_t OFF_WXH   = 33554432;      // bf16 [4096][1024]; after gateX: ctxp/ml scratch
  const size_t OFF_WXL   = 41943040;
  const size_t OFF_WOH   = 50331648;      // bf16 [1024][2048]
  const size_t OFF_WOL   = 54525952;
  const size_t OFF_XBH   = 58720256;      // bf16 [1024][1024]; after gateX: WaT hi
  const size_t OFF_XBL   = 60817408;      // after gateX: WaT lo
  const size_t OFF_GATEX = 62914560;      // f32 [32][32][4096]
  const size_t OFF_ZBH   = 79691776;      // bf16 [2][32][2048]
  const size_t OFF_ZBL   = 79953920;
  const size_t OFF_ZOH   = 80216064;      // bf16 [32][2048]
  const size_t OFF_ZOL   = 80347136;
  const size_t OFF_CBUF  = 80478208;      // f32 [32][1024]
  const size_t OFF_UBUF  = 80609280;      // f32 [32][1024]
  const size_t OFF_SC    = 80740352;      // f32 [32][400]
  const size_t WS_NEED   = 82939904;      // proven-OK base size
  if (ws_size < WS_NEED) return;  // fail loudly (poisoned output) rather than corrupt memory

  // enc-bf16 copy goes past the base if workspace allows
  const size_t OFF_ENCB  = WS_NEED;                 // bf16 [32][400][1024] = 26,214,400 B
  const size_t WS_BIG    = WS_NEED + 26214400;
  const bool use_bf16enc = (ws_size >= WS_BIG);

  // scratch aliases inside dead Wx region (dead after gemm128_bias_k)
  const size_t OFF_CTXP  = OFF_WXH;                 // f32 [32][16][1024] = 2 MB
  const size_t OFF_ML    = OFF_WXH + 2097152;       // f32 [32][16][2]

  char* ws = (char*)d_ws;
  u16*   Wrh   = (u16*)(ws + OFF_WRH);
  u16*   Wrl   = (u16*)(ws + OFF_WRL);
  u16*   Wxh   = (u16*)(ws + OFF_WXH);
  u16*   Wxl   = (u16*)(ws + OFF_WXL);
  u16*   Woh   = (u16*)(ws + OFF_WOH);
  u16*   Wol   = (u16*)(ws + OFF_WOL);
  u16*   Xbh   = (u16*)(ws + OFF_XBH);
  u16*   Xbl   = (u16*)(ws + OFF_XBL);
  u16*   Wth   = (u16*)(ws + OFF_XBH);   // alias: valid after gemm128_bias_k
  u16*   Wtl   = (u16*)(ws + OFF_XBL);
  float* gateX = (float*)(ws + OFF_GATEX);
  u16*   Zbh   = (u16*)(ws + OFF_ZBH);
  u16*   Zbl   = (u16*)(ws + OFF_ZBL);
  u16*   Zoh   = (u16*)(ws + OFF_ZOH);
  u16*   Zol   = (u16*)(ws + OFF_ZOL);
  float* cbuf  = (float*)(ws + OFF_CBUF);
  float* ubuf  = (float*)(ws + OFF_UBUF);
  float* sc    = (float*)(ws + OFF_SC);
  float* ctxp  = (float*)(ws + OFF_CTXP);
  float* mlbuf = (float*)(ws + OFF_ML);
  u16*   encb  = (u16*)(ws + OFF_ENCB);

  // ---- precompute (1 merged cast dispatch + GEMM + watsplit) ----
  cast_all_k<<<22195, 256, 0, stream>>>(W_ih, W_hh, W_out, input_,
      h0, c0, ha0, past, enc,
      Wxh, Wxl, Wrh, Wrl, Woh, Wol, Xbh, Xbl,
      Zbh, Zbl, cbuf, out + OUT_PAST, out + OUT_LOSS,
      encb, use_bf16enc ? 1 : 0);

  // gateX = Xb @ Wx^T + b_ih + b_hh   (M=1024, N=4096, K=1024)
  gemm128_bias_k<<<dim3(32, 8), 256, 0, stream>>>(Xbh, Xbl, Wxh, Wxl, gateX, b_ih, b_hh, 1024, 4096, 1024);
  // after gateX, Xb and Wx regions are dead -> WaT into Xb; ctxp/ml into Wx
  watsplit_k<<<dim3(32, 32), 256, 0, stream>>>(W_attn, Wth, Wtl);

  // ---- sequential decode: 5 dispatches per step, no cross-block sync ----
  for (int t = 0; t < 32; ++t){
    int p = t & 1;
    u16* Zih = Zbh + (size_t)p * 65536;
    u16* Zil = Zbl + (size_t)p * 65536;
    u16* Znh = Zbh + (size_t)(1-p) * 65536;
    u16* Znl = Zbl + (size_t)(1-p) * 65536;
    int last = (t == 31);
    rec_cell_k<<<512, 512, 0, stream>>>(Zih, Zil, Wrh, Wrl,
        gateX + (size_t)t*131072, cbuf, Znh, Znl, Zoh, Zol,
        out + OUT_H, out + OUT_C, last);
    u_mfma_k<<<128, 512, 0, stream>>>(Zoh, Zol, Wth, Wtl, ubuf);
    if (use_bf16enc)
      flash_bf16_k<<<512, 512, 0, stream>>>(encb, ubuf, sc, ctxp, mlbuf);
    else
      flash_f32_k<<<512, 512, 0, stream>>>(enc, ubuf, sc, ctxp, mlbuf);
    combine_k<<<256, 256, 0, stream>>>(sc, ctxp, mlbuf, Zoh, Zol,
        out + OUT_ATTN + (size_t)t*12800);
    outg_fused_k<<<128, 512, 0, stream>>>(Zoh, Zol, Woh, Wol,
        out + OUT_OUTPUT + (size_t)t*1024, Znh, Znl, out + OUT_HATTN, last);
  }
}

// Round 12
// 1395.153 us; speedup vs baseline: 1.1344x; 1.1344x over previous
//
#include <hip/hip_runtime.h>
#include <hip/hip_bf16.h>

using u16 = unsigned short;
typedef __attribute__((ext_vector_type(8))) short bf16x8;
typedef __attribute__((ext_vector_type(4))) float f32x4;
typedef __attribute__((ext_vector_type(4))) u16 u16x4;

// Sizes (fixed): B=32, T=32, S=400, H=1024, I=1024

__device__ __forceinline__ float bf2f(u16 u){ union{unsigned int i; float f;} v; v.i = ((unsigned int)u)<<16; return v.f; }
__device__ __forceinline__ u16 f2bf(float f){ __hip_bfloat16 h = __float2bfloat16(f); return *reinterpret_cast<u16*>(&h); }
struct HL { u16 h, l; };
__device__ __forceinline__ HL split1(float f){
  HL r; r.h = f2bf(f); r.l = f2bf(f - bf2f(r.h)); return r;
}
__device__ __forceinline__ f32x4 mfma16(bf16x8 a, bf16x8 b, f32x4 c){ return __builtin_amdgcn_mfma_f32_16x16x32_bf16(a,b,c,0,0,0); }

// ---------------- merged cast / init kernel (runs once per launch) ----------------
// block ranges: [0,8192) wih | [8192,12288) whh | [12288,14336) wout
//               [14336,15360) x | [15360,15795) misc | [15795,22195) encb
__global__ __launch_bounds__(256) void cast_all_k(
    const float* __restrict__ Wih, const float* __restrict__ Whh,
    const float* __restrict__ Wout_f, const float* __restrict__ inp,
    const float* __restrict__ h0, const float* __restrict__ c0,
    const float* __restrict__ ha0, const float* __restrict__ past,
    const float* __restrict__ enc,
    u16* __restrict__ Wxh, u16* __restrict__ Wxl, u16* __restrict__ Wrh, u16* __restrict__ Wrl,
    u16* __restrict__ Woh, u16* __restrict__ Wol,
    u16* __restrict__ Xh, u16* __restrict__ Xl,
    u16* __restrict__ Zh0, u16* __restrict__ Zl0, float* __restrict__ cbuf,
    float* __restrict__ out_past, float* __restrict__ out_loss,
    u16* __restrict__ encb, int do_encb)
{
  const int blk = blockIdx.x;
  if (blk < 8192){
    int v = blk*256 + threadIdx.x;
    int flat = v*4; int j = flat >> 11; int k = flat & 2047;
    float4 f = *(const float4*)(Wih + flat);
    HL s0 = split1(f.x), s1 = split1(f.y), s2 = split1(f.z), s3 = split1(f.w);
    u16x4 h, l;
    h[0]=s0.h; h[1]=s1.h; h[2]=s2.h; h[3]=s3.h;
    l[0]=s0.l; l[1]=s1.l; l[2]=s2.l; l[3]=s3.l;
    if (k < 1024){
      *(u16x4*)(Wxh + (size_t)j*1024 + k) = h;
      *(u16x4*)(Wxl + (size_t)j*1024 + k) = l;
    } else {
      *(u16x4*)(Wrh + (size_t)j*2048 + (k-1024)) = h;
      *(u16x4*)(Wrl + (size_t)j*2048 + (k-1024)) = l;
    }
  } else if (blk < 12288){
    int v = (blk-8192)*256 + threadIdx.x;
    int flat = v*4; int j = flat >> 10; int k = flat & 1023;
    float4 f = *(const float4*)(Whh + flat);
    HL s0 = split1(f.x), s1 = split1(f.y), s2 = split1(f.z), s3 = split1(f.w);
    u16x4 h, l;
    h[0]=s0.h; h[1]=s1.h; h[2]=s2.h; h[3]=s3.h;
    l[0]=s0.l; l[1]=s1.l; l[2]=s2.l; l[3]=s3.l;
    *(u16x4*)(Wrh + (size_t)j*2048 + 1024 + k) = h;
    *(u16x4*)(Wrl + (size_t)j*2048 + 1024 + k) = l;
  } else if (blk < 14336){
    int v = (blk-12288)*256 + threadIdx.x;
    float4 f = *(const float4*)(Wout_f + (size_t)v*4);
    HL s0 = split1(f.x), s1 = split1(f.y), s2 = split1(f.z), s3 = split1(f.w);
    u16x4 h, l;
    h[0]=s0.h; h[1]=s1.h; h[2]=s2.h; h[3]=s3.h;
    l[0]=s0.l; l[1]=s1.l; l[2]=s2.l; l[3]=s3.l;
    *(u16x4*)(Woh + (size_t)v*4) = h;
    *(u16x4*)(Wol + (size_t)v*4) = l;
  } else if (blk < 15360){
    int v = (blk-14336)*256 + threadIdx.x;
    int flat = v*4; int m = flat >> 10; int k = flat & 1023;
    int t = m >> 5, b = m & 31;
    float4 f = *(const float4*)(inp + ((size_t)(b*32 + t) << 10) + k);
    HL s0 = split1(f.x), s1 = split1(f.y), s2 = split1(f.z), s3 = split1(f.w);
    u16x4 h, l;
    h[0]=s0.h; h[1]=s1.h; h[2]=s2.h; h[3]=s3.h;
    l[0]=s0.l; l[1]=s1.l; l[2]=s2.l; l[3]=s3.l;
    *(u16x4*)(Xh + flat) = h;
    *(u16x4*)(Xl + flat) = l;
  } else if (blk < 15795){
    int idx = (blk-15360)*256 + threadIdx.x;
    if (idx < 65536){
      int b = idx >> 11, col = idx & 2047;
      float v = (col < 1024) ? ha0[b*1024 + col] : h0[b*1024 + col - 1024];
      HL s = split1(v);
      Zh0[idx] = s.h; Zl0[idx] = s.l;
    } else if (idx < 65536 + 32768){
      int i = idx - 65536; cbuf[i] = c0[i];
    } else if (idx < 65536 + 32768 + 12800){
      int i = idx - 98304; out_past[i] = past[i];
    } else if (idx == 65536 + 32768 + 12800){
      out_loss[0] = 0.f;
    }
  } else {
    if (!do_encb) return;
    int v = (blk-15795)*256 + threadIdx.x;
    size_t flat = (size_t)v*8;
    int c = flat & 1023; int rem = flat >> 10;   // rem = s*32 + b
    int b = rem & 31, s = rem >> 5;
    float4 f0 = *(const float4*)(enc + flat);
    float4 f1 = *(const float4*)(enc + flat + 4);
    u16x4 h0v, h1v;
    h0v[0]=f2bf(f0.x); h0v[1]=f2bf(f0.y); h0v[2]=f2bf(f0.z); h0v[3]=f2bf(f0.w);
    h1v[0]=f2bf(f1.x); h1v[1]=f2bf(f1.y); h1v[2]=f2bf(f1.z); h1v[3]=f2bf(f1.w);
    u16* dst = encb + ((size_t)b*400 + s)*1024 + c;
    *(u16x4*)dst = h0v;
    *(u16x4*)(dst+4) = h1v;
  }
}

// W_attn [g][c] -> WaT [c][g] split hi/lo
__global__ __launch_bounds__(256) void watsplit_k(const float* __restrict__ Wattn,
    u16* __restrict__ Wth, u16* __restrict__ Wtl){
  __shared__ float t[32][33];
  int gx = blockIdx.x, cx = blockIdx.y;
  int ty = threadIdx.x >> 5, tx = threadIdx.x & 31;
  #pragma unroll
  for (int i=0;i<4;++i){
    int g = gx*32 + ty + i*8;
    t[ty+i*8][tx] = Wattn[(size_t)g*1024 + cx*32 + tx];
  }
  __syncthreads();
  #pragma unroll
  for (int i=0;i<4;++i){
    int c = cx*32 + ty + i*8;
    HL s = split1(t[tx][ty+i*8]);
    Wth[(size_t)c*1024 + gx*32 + tx] = s.h;
    Wtl[(size_t)c*1024 + gx*32 + tx] = s.l;
  }
}

// ---------------- 128x128 split-precision MFMA GEMM (x-path precompute) ----------------
__global__ __launch_bounds__(256) void gemm128_bias_k(
    const u16* __restrict__ Ah, const u16* __restrict__ Al,
    const u16* __restrict__ Bh, const u16* __restrict__ Bl, float* __restrict__ C,
    const float* __restrict__ bias0, const float* __restrict__ bias1, int M, int N, int K)
{
  __shared__ __align__(16) u16 Ash[4096], Asl[4096], Bsh[4096], Bsl[4096];
  const int tid = threadIdx.x;
  const int lane = tid & 63, w = tid >> 6;
  const int wm = w >> 1, wn = w & 1;
  const int m0 = blockIdx.y * 128, n0 = blockIdx.x * 128;
  const int r = lane & 15, q = lane >> 4;

  f32x4 acc[4][4];
  #pragma unroll
  for (int i=0;i<4;i++)
    #pragma unroll
    for (int j=0;j<4;j++) acc[i][j] = (f32x4){0.f,0.f,0.f,0.f};

  const int NT = K >> 5;
  const int srow = tid >> 2;
  const int skp  = (tid & 3) * 8;
  bf16x8 rah0, rah1, ral0, ral1, rbh0, rbh1, rbl0, rbl1;

  {
    size_t ao = (size_t)(m0 + srow) * K + skp;
    size_t bo = (size_t)(n0 + srow) * K + skp;
    rah0 = *(const bf16x8*)(Ah + ao);  rah1 = *(const bf16x8*)(Ah + ao + (size_t)64*K);
    ral0 = *(const bf16x8*)(Al + ao);  ral1 = *(const bf16x8*)(Al + ao + (size_t)64*K);
    rbh0 = *(const bf16x8*)(Bh + bo);  rbh1 = *(const bf16x8*)(Bh + bo + (size_t)64*K);
    rbl0 = *(const bf16x8*)(Bl + bo);  rbl1 = *(const bf16x8*)(Bl + bo + (size_t)64*K);
  }

  for (int kt = 0; kt < NT; ++kt){
    __syncthreads();
    *(bf16x8*)(Ash + tid*8)        = rah0;
    *(bf16x8*)(Ash + 2048 + tid*8) = rah1;
    *(bf16x8*)(Asl + tid*8)        = ral0;
    *(bf16x8*)(Asl + 2048 + tid*8) = ral1;
    *(bf16x8*)(Bsh + tid*8)        = rbh0;
    *(bf16x8*)(Bsh + 2048 + tid*8) = rbh1;
    *(bf16x8*)(Bsl + tid*8)        = rbl0;
    *(bf16x8*)(Bsl + 2048 + tid*8) = rbl1;
    __syncthreads();
    if (kt + 1 < NT){
      size_t ao = (size_t)(m0 + srow) * K + (kt+1)*32 + skp;
      size_t bo = (size_t)(n0 + srow) * K + (kt+1)*32 + skp;
      rah0 = *(const bf16x8*)(Ah + ao);  rah1 = *(const bf16x8*)(Ah + ao + (size_t)64*K);
      ral0 = *(const bf16x8*)(Al + ao);  ral1 = *(const bf16x8*)(Al + ao + (size_t)64*K);
      rbh0 = *(const bf16x8*)(Bh + bo);  rbh1 = *(const bf16x8*)(Bh + bo + (size_t)64*K);
      rbl0 = *(const bf16x8*)(Bl + bo);  rbl1 = *(const bf16x8*)(Bl + bo + (size_t)64*K);
    }
    bf16x8 afh[4], afl[4], bfh[4], bfl[4];
    #pragma unroll
    for (int mf=0; mf<4; ++mf){
      int off = (wm*64 + mf*16 + r)*32 + q*8;
      afh[mf] = *(const bf16x8*)(Ash + off);
      afl[mf] = *(const bf16x8*)(Asl + off);
    }
    #pragma unroll
    for (int nf=0; nf<4; ++nf){
      int off = (wn*64 + nf*16 + r)*32 + q*8;
      bfh[nf] = *(const bf16x8*)(Bsh + off);
      bfl[nf] = *(const bf16x8*)(Bsl + off);
    }
    #pragma unroll
    for (int mf=0; mf<4; ++mf)
      #pragma unroll
      for (int nf=0; nf<4; ++nf){
        acc[mf][nf] = mfma16(afh[mf], bfh[nf], acc[mf][nf]);
        acc[mf][nf] = mfma16(afh[mf], bfl[nf], acc[mf][nf]);
        acc[mf][nf] = mfma16(afl[mf], bfh[nf], acc[mf][nf]);
      }
  }

  #pragma unroll
  for (int mf=0; mf<4; ++mf)
    #pragma unroll
    for (int nf=0; nf<4; ++nf)
      #pragma unroll
      for (int rr=0; rr<4; ++rr){
        int row = m0 + wm*64 + mf*16 + q*4 + rr;
        int col = n0 + wn*64 + nf*16 + r;
        C[(size_t)row*N + col] = acc[mf][nf][rr] + bias0[col] + bias1[col];
      }
}

// ---------------- per-step kernels (5 dispatches, no cross-block sync) ----------------

// Fused recurrent GEMM + LSTM cell, single dispatch, full-K per block.
// 256 blocks: block j4 computes cols j4*4..+3 of ALL FOUR gates (16 MFMA cols),
// K=2048 split over 8 waves (256 each), LDS reduce, cell math in-block.
__global__ __launch_bounds__(512) void rec_cell_k(
    const u16* __restrict__ Zh, const u16* __restrict__ Zl,
    const u16* __restrict__ Wh, const u16* __restrict__ Wl,
    const float* __restrict__ gX, float* __restrict__ cbuf,
    u16* __restrict__ Znh, u16* __restrict__ Znl,
    u16* __restrict__ Zoh, u16* __restrict__ Zol,
    float* __restrict__ out_h, float* __restrict__ out_c, int last)
{
  __shared__ float red[8][512];
  __shared__ float gsum[512];
  const int tid = threadIdx.x, lane = tid & 63, w = tid >> 6;
  const int j4 = blockIdx.x;           // 0..255
  const int r = lane & 15, q = lane >> 4;
  const int k0 = w*256;

  f32x4 acc0 = (f32x4){0,0,0,0}, acc1 = (f32x4){0,0,0,0};
  const size_t aoff = (size_t)r*2048 + k0 + q*8;
  // B fragment row r -> Wrec row (r>>2)*1024 + j4*4 + (r&3)   (4 rows per gate)
  const size_t boff = (size_t)((r>>2)*1024 + j4*4 + (r&3))*2048 + k0 + q*8;
  #pragma unroll
  for (int kt = 0; kt < 8; ++kt){
    bf16x8 a0h = *(const bf16x8*)(Zh + aoff + kt*32);
    bf16x8 a0l = *(const bf16x8*)(Zl + aoff + kt*32);
    bf16x8 a1h = *(const bf16x8*)(Zh + aoff + (size_t)16*2048 + kt*32);
    bf16x8 a1l = *(const bf16x8*)(Zl + aoff + (size_t)16*2048 + kt*32);
    bf16x8 bh  = *(const bf16x8*)(Wh + boff + kt*32);
    bf16x8 bl  = *(const bf16x8*)(Wl + boff + kt*32);
    acc0 = mfma16(a0h, bh, acc0);
    acc0 = mfma16(a0h, bl, acc0);
    acc0 = mfma16(a0l, bh, acc0);
    acc1 = mfma16(a1h, bh, acc1);
    acc1 = mfma16(a1h, bl, acc1);
    acc1 = mfma16(a1l, bh, acc1);
  }
  #pragma unroll
  for (int rr=0; rr<4; ++rr){
    red[w][(q*4+rr)*16 + r]        = acc0[rr];   // b 0..15
    red[w][256 + (q*4+rr)*16 + r]  = acc1[rr];   // b 16..31
  }
  __syncthreads();
  {
    // gsum[b*16 + (g*4+c)] = full-K gate partial
    float v = 0.f;
    #pragma unroll
    for (int w2=0; w2<8; ++w2) v += red[w2][tid];
    gsum[tid] = v;
  }
  __syncthreads();
  if (tid < 128){
    int b = tid >> 2, c = tid & 3;
    int j = j4*4 + c;
    float gs[4];
    #pragma unroll
    for (int g=0; g<4; ++g)
      gs[g] = gsum[b*16 + g*4 + c] + gX[(size_t)b*4096 + g*1024 + j];
    int idx = b*1024 + j;
    float iv = 1.f/(1.f + expf(-gs[0]));
    float fv = 1.f/(1.f + expf(-gs[1]));
    float gv = tanhf(gs[2]);
    float ov = 1.f/(1.f + expf(-gs[3]));
    float cn = fv * cbuf[idx] + iv*gv;
    cbuf[idx] = cn;
    float h = ov * tanhf(cn);
    HL s = split1(h);
    size_t zi = (size_t)b*2048 + 1024 + j;
    Znh[zi] = s.h; Znl[zi] = s.l;
    Zoh[zi] = s.h; Zol[zi] = s.l;
    if (last){ out_h[idx] = h; out_c[idx] = cn; }
  }
}

// u[b,c] = sum_g h[b,g] * W_attn[g,c] via split MFMA vs transposed WaT.
__global__ __launch_bounds__(512) void u_mfma_k(
    const u16* __restrict__ Zoh, const u16* __restrict__ Zol,
    const u16* __restrict__ Wth, const u16* __restrict__ Wtl,
    float* __restrict__ ubuf)
{
  __shared__ float red[8][512];
  const int tid = threadIdx.x, lane = tid & 63, w = tid >> 6;
  const int cc = blockIdx.x;   // 0..63
  const int r = lane & 15, q = lane >> 4;
  f32x4 acc0 = (f32x4){0,0,0,0}, acc1 = (f32x4){0,0,0,0};
  const size_t aoff = (size_t)r*2048 + 1024 + w*128 + q*8;
  const size_t boff = (size_t)(cc*16 + r)*1024 + w*128 + q*8;
  #pragma unroll
  for (int kt=0; kt<4; ++kt){
    bf16x8 a0h = *(const bf16x8*)(Zoh + aoff + kt*32);
    bf16x8 a0l = *(const bf16x8*)(Zol + aoff + kt*32);
    bf16x8 a1h = *(const bf16x8*)(Zoh + aoff + (size_t)16*2048 + kt*32);
    bf16x8 a1l = *(const bf16x8*)(Zol + aoff + (size_t)16*2048 + kt*32);
    bf16x8 bh  = *(const bf16x8*)(Wth + boff + kt*32);
    bf16x8 bl  = *(const bf16x8*)(Wtl + boff + kt*32);
    acc0 = mfma16(a0h, bh, acc0);
    acc0 = mfma16(a0h, bl, acc0);
    acc0 = mfma16(a0l, bh, acc0);
    acc1 = mfma16(a1h, bh, acc1);
    acc1 = mfma16(a1h, bl, acc1);
    acc1 = mfma16(a1l, bh, acc1);
  }
  #pragma unroll
  for (int rr=0; rr<4; ++rr){
    red[w][(q*4+rr)*16 + r]      = acc0[rr];
    red[w][(16 + q*4+rr)*16 + r] = acc1[rr];
  }
  __syncthreads();
  {
    int b = tid >> 4, jj = tid & 15;
    float v = 0.f;
    #pragma unroll
    for (int w2=0; w2<8; ++w2) v += red[w2][tid];
    ubuf[(size_t)b*1024 + cc*16 + jj] = v;
  }
}

// Flash attention pass, bf16 enc: 512 blocks = (32 b x 16 s-chunks of 25).
__global__ __launch_bounds__(512) void flash_bf16_k(const u16* __restrict__ encb,
    const float* __restrict__ ubuf, float* __restrict__ scbuf,
    float* __restrict__ ctxp, float* __restrict__ mlbuf)
{
  __shared__ float wacc[8][1024];
  __shared__ float wml[16];
  const int tid = threadIdx.x, lane = tid & 63, w = tid >> 6;
  const int b = blockIdx.x >> 4, sc16 = blockIdx.x & 15;
  const int s0 = sc16 * 25;

  const float* up = ubuf + (size_t)b*1024 + lane*16;
  float uu[16];
  #pragma unroll
  for (int i=0;i<4;i++){ float4 t4 = *(const float4*)(up + i*4); uu[4*i]=t4.x; uu[4*i+1]=t4.y; uu[4*i+2]=t4.z; uu[4*i+3]=t4.w; }

  float m = -1e30f, l = 0.f;
  float acc[16];
  #pragma unroll
  for (int i=0;i<16;i++) acc[i] = 0.f;

  for (int s = s0 + w; s < s0 + 25; s += 8){
    const u16* ep = encb + ((size_t)b*400 + s)*1024 + lane*16;
    bf16x8 e0 = *(const bf16x8*)ep;
    bf16x8 e1 = *(const bf16x8*)(ep + 8);
    float er[16];
    #pragma unroll
    for (int i=0;i<8;i++){ er[i] = bf2f((u16)e0[i]); er[8+i] = bf2f((u16)e1[i]); }
    float sc = 0.f;
    #pragma unroll
    for (int i=0;i<16;i++) sc = fmaf(er[i], uu[i], sc);
    #pragma unroll
    for (int off=32; off; off>>=1) sc += __shfl_xor(sc, off);
    if (lane == 0) scbuf[(size_t)b*400 + s] = sc;
    if (sc > m){
      float f = expf(m - sc);
      l *= f;
      #pragma unroll
      for (int i=0;i<16;i++) acc[i] *= f;
      m = sc;
    }
    float wgt = expf(sc - m);
    l += wgt;
    #pragma unroll
    for (int i=0;i<16;i++) acc[i] = fmaf(wgt, er[i], acc[i]);
  }

  #pragma unroll
  for (int i=0;i<16;i++) wacc[w][lane*16+i] = acc[i];
  if (lane == 0){ wml[w*2] = m; wml[w*2+1] = l; }
  __syncthreads();

  float M = wml[0];
  #pragma unroll
  for (int i=1;i<8;i++) M = fmaxf(M, wml[i*2]);
  float c0v = 0.f, c1v = 0.f;
  #pragma unroll
  for (int i=0;i<8;i++){
    float f = expf(wml[i*2] - M);
    c0v = fmaf(wacc[i][tid],       f, c0v);
    c1v = fmaf(wacc[i][tid + 512], f, c1v);
  }
  size_t co = ((size_t)b*16 + sc16)*1024;
  ctxp[co + tid]       = c0v;
  ctxp[co + tid + 512] = c1v;
  if (tid == 0){
    float L = 0.f;
    #pragma unroll
    for (int i=0;i<8;i++) L += wml[i*2+1] * expf(wml[i*2] - M);
    mlbuf[((size_t)b*16 + sc16)*2]     = M;
    mlbuf[((size_t)b*16 + sc16)*2 + 1] = L;
  }
}

// Flash attention pass, f32 enc fallback (same chunking): 512 blocks.
__global__ __launch_bounds__(512) void flash_f32_k(const float* __restrict__ enc,
    const float* __restrict__ ubuf, float* __restrict__ scbuf,
    float* __restrict__ ctxp, float* __restrict__ mlbuf)
{
  __shared__ float wacc[8][1024];
  __shared__ float wml[16];
  const int tid = threadIdx.x, lane = tid & 63, w = tid >> 6;
  const int b = blockIdx.x >> 4, sc16 = blockIdx.x & 15;
  const int s0 = sc16 * 25;

  const float* up = ubuf + (size_t)b*1024 + lane*16;
  float uu[16];
  #pragma unroll
  for (int i=0;i<4;i++){ float4 t4 = *(const float4*)(up + i*4); uu[4*i]=t4.x; uu[4*i+1]=t4.y; uu[4*i+2]=t4.z; uu[4*i+3]=t4.w; }

  float m = -1e30f, l = 0.f;
  float acc[16];
  #pragma unroll
  for (int i=0;i<16;i++) acc[i] = 0.f;

  for (int s = s0 + w; s < s0 + 25; s += 8){
    const float* ep = enc + ((size_t)s*32 + b)*1024 + lane*16;
    float er[16];
    #pragma unroll
    for (int i=0;i<4;i++){ float4 e4 = *(const float4*)(ep + i*4); er[4*i]=e4.x; er[4*i+1]=e4.y; er[4*i+2]=e4.z; er[4*i+3]=e4.w; }
    float sc = 0.f;
    #pragma unroll
    for (int i=0;i<16;i++) sc = fmaf(er[i], uu[i], sc);
    #pragma unroll
    for (int off=32; off; off>>=1) sc += __shfl_xor(sc, off);
    if (lane == 0) scbuf[(size_t)b*400 + s] = sc;
    if (sc > m){
      float f = expf(m - sc);
      l *= f;
      #pragma unroll
      for (int i=0;i<16;i++) acc[i] *= f;
      m = sc;
    }
    float wgt = expf(sc - m);
    l += wgt;
    #pragma unroll
    for (int i=0;i<16;i++) acc[i] = fmaf(wgt, er[i], acc[i]);
  }

  #pragma unroll
  for (int i=0;i<16;i++) wacc[w][lane*16+i] = acc[i];
  if (lane == 0){ wml[w*2] = m; wml[w*2+1] = l; }
  __syncthreads();

  float M = wml[0];
  #pragma unroll
  for (int i=1;i<8;i++) M = fmaxf(M, wml[i*2]);
  float c0v = 0.f, c1v = 0.f;
  #pragma unroll
  for (int i=0;i<8;i++){
    float f = expf(wml[i*2] - M);
    c0v = fmaf(wacc[i][tid],       f, c0v);
    c1v = fmaf(wacc[i][tid + 512], f, c1v);
  }
  size_t co = ((size_t)b*16 + sc16)*1024;
  ctxp[co + tid]       = c0v;
  ctxp[co + tid + 512] = c1v;
  if (tid == 0){
    float L = 0.f;
    #pragma unroll
    for (int i=0;i<8;i++) L += wml[i*2+1] * expf(wml[i*2] - M);
    mlbuf[((size_t)b*16 + sc16)*2]     = M;
    mlbuf[((size_t)b*16 + sc16)*2 + 1] = L;
  }
}

// Combine 16 chunk partials: global (M,L), ctx -> Z split, attn output row.
__global__ __launch_bounds__(256) void combine_k(const float* __restrict__ scbuf,
    const float* __restrict__ ctxp, const float* __restrict__ mlbuf,
    u16* __restrict__ Zoh, u16* __restrict__ Zol, float* __restrict__ attn_out)
{
  const int b = blockIdx.x >> 3, cc = blockIdx.x & 7;
  const int tid = threadIdx.x;
  float M = -1e30f;
  #pragma unroll
  for (int i=0;i<16;i++) M = fmaxf(M, mlbuf[((size_t)b*16 + i)*2]);
  float L = 0.f;
  #pragma unroll
  for (int i=0;i<16;i++) L += mlbuf[((size_t)b*16 + i)*2 + 1] * expf(mlbuf[((size_t)b*16 + i)*2] - M);
  float invL = 1.f / L;
  if (tid < 128){
    int col = cc*128 + tid;
    float v = 0.f;
    #pragma unroll
    for (int i=0;i<16;i++)
      v = fmaf(ctxp[((size_t)b*16 + i)*1024 + col], expf(mlbuf[((size_t)b*16 + i)*2] - M), v);
    HL s = split1(v * invL);
    size_t zi = (size_t)b*2048 + col;
    Zoh[zi] = s.h; Zol[zi] = s.l;
  } else if (tid < 128 + 50){
    int s = cc*50 + (tid - 128);
    attn_out[(size_t)b*400 + s] = expf(scbuf[(size_t)b*400 + s] - M) * invL;
  }
}

// Fused full-K out-GEMM + tanh, single dispatch, no partial buffers.
// 128 blocks = (64 ub col-groups) x (2 bh row-halves); 8 waves K-split (256 each).
__global__ __launch_bounds__(512) void outg_fused_k(
    const u16* __restrict__ Zoh, const u16* __restrict__ Zol,
    const u16* __restrict__ Woh, const u16* __restrict__ Wol,
    float* __restrict__ out_outp /* + t*1024 */, u16* __restrict__ Znh, u16* __restrict__ Znl,
    float* __restrict__ out_hattn, int last)
{
  __shared__ float red[8][256];
  const int tid = threadIdx.x, lane = tid & 63, w = tid >> 6;
  const int ub = blockIdx.x & 63, bh = blockIdx.x >> 6;
  const int r = lane & 15, q = lane >> 4;
  const int k0 = w*256;
  f32x4 acc0 = (f32x4){0,0,0,0};
  const size_t aoff = (size_t)(bh*16 + r)*2048 + k0 + q*8;
  const size_t boff = (size_t)(ub*16 + r)*2048 + k0 + q*8;
  #pragma unroll
  for (int kt=0; kt<8; ++kt){
    bf16x8 ah = *(const bf16x8*)(Zoh + aoff + kt*32);
    bf16x8 al = *(const bf16x8*)(Zol + aoff + kt*32);
    bf16x8 bh_ = *(const bf16x8*)(Woh + boff + kt*32);
    bf16x8 bl_ = *(const bf16x8*)(Wol + boff + kt*32);
    acc0 = mfma16(ah, bh_, acc0);
    acc0 = mfma16(ah, bl_, acc0);
    acc0 = mfma16(al, bh_, acc0);
  }
  #pragma unroll
  for (int rr=0; rr<4; ++rr)
    red[w][(q*4+rr)*16 + r] = acc0[rr];
  __syncthreads();
  if (tid < 256){
    int bloc = tid >> 4, jj = tid & 15;
    float z = 0.f;
    #pragma unroll
    for (int w2=0; w2<8; ++w2) z += red[w2][tid];
    int b = bh*16 + bloc;
    int u = ub*16 + jj;
    float ha = tanhf(z);
    out_outp[(size_t)b*32768 + u] = ha;
    HL s = split1(ha);
    Znh[(size_t)b*2048 + u] = s.h;
    Znl[(size_t)b*2048 + u] = s.l;
    if (last) out_hattn[(size_t)b*1024 + u] = ha;
  }
}

// ---------------- launch ----------------

extern "C" void kernel_launch(void* const* d_in, const int* in_sizes, int n_in,
                              void* d_out, int out_size, void* d_ws, size_t ws_size,
                              hipStream_t stream)
{
  const float* input_ = (const float*)d_in[0];
  const float* h0     = (const float*)d_in[1];
  const float* c0     = (const float*)d_in[2];
  const float* ha0    = (const float*)d_in[3];
  const float* enc    = (const float*)d_in[4];
  const float* past   = (const float*)d_in[5];
  const float* W_ih   = (const float*)d_in[6];
  const float* W_hh   = (const float*)d_in[7];
  const float* b_ih   = (const float*)d_in[8];
  const float* b_hh   = (const float*)d_in[9];
  const float* W_attn = (const float*)d_in[10];
  const float* W_out  = (const float*)d_in[11];
  float* out = (float*)d_out;

  // d_out layout (floats)
  const size_t OUT_OUTPUT = 0;            // [32][32][1024]
  const size_t OUT_H      = 1048576;
  const size_t OUT_C      = 1081344;
  const size_t OUT_HATTN  = 1114112;
  const size_t OUT_ATTN   = 1146880;      // [32][32][400]
  const size_t OUT_PAST   = 1556480;
  const size_t OUT_LOSS   = 1569280;

  // workspace layout (bytes)
  const size_t OFF_WRH   = 0;             // bf16 [4096][2048] hi
  const size_t OFF_WRL   = 16777216;
  const size_t OFF_WXH   = 33554432;      // bf16 [4096][1024]; after gateX: ctxp/ml scratch
  const size_t OFF_WXL   = 41943040;
  const size_t OFF_WOH   = 50331648;      // bf16 [1024][2048]
  const size_t OFF_WOL   = 54525952;
  const size_t OFF_XBH   = 58720256;      // bf16 [1024][1024]; after gateX: WaT hi
  const size_t OFF_XBL   = 60817408;      // after gateX: WaT lo
  const size_t OFF_GATEX = 62914560;      // f32 [32][32][4096]
  const size_t OFF_ZBH   = 79691776;      // bf16 [2][32][2048]
  const size_t OFF_ZBL   = 79953920;
  const size_t OFF_ZOH   = 80216064;      // bf16 [32][2048]
  const size_t OFF_ZOL   = 80347136;
  const size_t OFF_CBUF  = 80478208;      // f32 [32][1024]
  const size_t OFF_UBUF  = 80609280;      // f32 [32][1024]
  const size_t OFF_SC    = 80740352;      // f32 [32][400]
  const size_t WS_NEED   = 82939904;      // proven-OK base size
  if (ws_size < WS_NEED) return;  // fail loudly (poisoned output) rather than corrupt memory

  // enc-bf16 copy goes past the base if workspace allows
  const size_t OFF_ENCB  = WS_NEED;                 // bf16 [32][400][1024] = 26,214,400 B
  const size_t WS_BIG    = WS_NEED + 26214400;
  const bool use_bf16enc = (ws_size >= WS_BIG);

  // scratch aliases inside dead Wx region (dead after gemm128_bias_k)
  const size_t OFF_CTXP  = OFF_WXH;                 // f32 [32][16][1024] = 2 MB
  const size_t OFF_ML    = OFF_WXH + 2097152;       // f32 [32][16][2]

  char* ws = (char*)d_ws;
  u16*   Wrh   = (u16*)(ws + OFF_WRH);
  u16*   Wrl   = (u16*)(ws + OFF_WRL);
  u16*   Wxh   = (u16*)(ws + OFF_WXH);
  u16*   Wxl   = (u16*)(ws + OFF_WXL);
  u16*   Woh   = (u16*)(ws + OFF_WOH);
  u16*   Wol   = (u16*)(ws + OFF_WOL);
  u16*   Xbh   = (u16*)(ws + OFF_XBH);
  u16*   Xbl   = (u16*)(ws + OFF_XBL);
  u16*   Wth   = (u16*)(ws + OFF_XBH);   // alias: valid after gemm128_bias_k
  u16*   Wtl   = (u16*)(ws + OFF_XBL);
  float* gateX = (float*)(ws + OFF_GATEX);
  u16*   Zbh   = (u16*)(ws + OFF_ZBH);
  u16*   Zbl   = (u16*)(ws + OFF_ZBL);
  u16*   Zoh   = (u16*)(ws + OFF_ZOH);
  u16*   Zol   = (u16*)(ws + OFF_ZOL);
  float* cbuf  = (float*)(ws + OFF_CBUF);
  float* ubuf  = (float*)(ws + OFF_UBUF);
  float* sc    = (float*)(ws + OFF_SC);
  float* ctxp  = (float*)(ws + OFF_CTXP);
  float* mlbuf = (float*)(ws + OFF_ML);
  u16*   encb  = (u16*)(ws + OFF_ENCB);

  // ---- precompute (1 merged cast dispatch + GEMM + watsplit) ----
  cast_all_k<<<22195, 256, 0, stream>>>(W_ih, W_hh, W_out, input_,
      h0, c0, ha0, past, enc,
      Wxh, Wxl, Wrh, Wrl, Woh, Wol, Xbh, Xbl,
      Zbh, Zbl, cbuf, out + OUT_PAST, out + OUT_LOSS,
      encb, use_bf16enc ? 1 : 0);

  // gateX = Xb @ Wx^T + b_ih + b_hh   (M=1024, N=4096, K=1024)
  gemm128_bias_k<<<dim3(32, 8), 256, 0, stream>>>(Xbh, Xbl, Wxh, Wxl, gateX, b_ih, b_hh, 1024, 4096, 1024);
  // after gateX, Xb and Wx regions are dead -> WaT into Xb; ctxp/ml into Wx
  watsplit_k<<<dim3(32, 32), 256, 0, stream>>>(W_attn, Wth, Wtl);

  // ---- sequential decode: 5 dispatches per step, no cross-block sync ----
  for (int t = 0; t < 32; ++t){
    int p = t & 1;
    u16* Zih = Zbh + (size_t)p * 65536;
    u16* Zil = Zbl + (size_t)p * 65536;
    u16* Znh = Zbh + (size_t)(1-p) * 65536;
    u16* Znl = Zbl + (size_t)(1-p) * 65536;
    int last = (t == 31);
    rec_cell_k<<<256, 512, 0, stream>>>(Zih, Zil, Wrh, Wrl,
        gateX + (size_t)t*131072, cbuf, Znh, Znl, Zoh, Zol,
        out + OUT_H, out + OUT_C, last);
    u_mfma_k<<<64, 512, 0, stream>>>(Zoh, Zol, Wth, Wtl, ubuf);
    if (use_bf16enc)
      flash_bf16_k<<<512, 512, 0, stream>>>(encb, ubuf, sc, ctxp, mlbuf);
    else
      flash_f32_k<<<512, 512, 0, stream>>>(enc, ubuf, sc, ctxp, mlbuf);
    combine_k<<<256, 256, 0, stream>>>(sc, ctxp, mlbuf, Zoh, Zol,
        out + OUT_ATTN + (size_t)t*12800);
    outg_fused_k<<<128, 512, 0, stream>>>(Zoh, Zol, Woh, Wol,
        out + OUT_OUTPUT + (size_t)t*1024, Znh, Znl, out + OUT_HATTN, last);
  }
}

// Round 13
// 1333.096 us; speedup vs baseline: 1.1872x; 1.0466x over previous
//
#include <hip/hip_runtime.h>
#include <hip/hip_bf16.h>

using u16 = unsigned short;
typedef __attribute__((ext_vector_type(8))) short bf16x8;
typedef __attribute__((ext_vector_type(4))) float f32x4;
typedef __attribute__((ext_vector_type(4))) u16 u16x4;

// Sizes (fixed): B=32, T=32, S=400, H=1024, I=1024

__device__ __forceinline__ float bf2f(u16 u){ union{unsigned int i; float f;} v; v.i = ((unsigned int)u)<<16; return v.f; }
__device__ __forceinline__ u16 f2bf(float f){ __hip_bfloat16 h = __float2bfloat16(f); return *reinterpret_cast<u16*>(&h); }
struct HL { u16 h, l; };
__device__ __forceinline__ HL split1(float f){
  HL r; r.h = f2bf(f); r.l = f2bf(f - bf2f(r.h)); return r;
}
__device__ __forceinline__ f32x4 mfma16(bf16x8 a, bf16x8 b, f32x4 c){ return __builtin_amdgcn_mfma_f32_16x16x32_bf16(a,b,c,0,0,0); }

// ---------------- merged cast / init kernel (runs once per launch) ----------------
// block ranges: [0,8192) wih | [8192,12288) whh | [12288,14336) wout
//               [14336,15360) x | [15360,15795) misc | [15795,22195) encb
__global__ __launch_bounds__(256) void cast_all_k(
    const float* __restrict__ Wih, const float* __restrict__ Whh,
    const float* __restrict__ Wout_f, const float* __restrict__ inp,
    const float* __restrict__ h0, const float* __restrict__ c0,
    const float* __restrict__ ha0, const float* __restrict__ past,
    const float* __restrict__ enc,
    u16* __restrict__ Wxh, u16* __restrict__ Wxl, u16* __restrict__ Wrh, u16* __restrict__ Wrl,
    u16* __restrict__ Woh, u16* __restrict__ Wol,
    u16* __restrict__ Xh, u16* __restrict__ Xl,
    u16* __restrict__ Zh0, u16* __restrict__ Zl0, float* __restrict__ cbuf,
    float* __restrict__ out_past, float* __restrict__ out_loss,
    u16* __restrict__ encb, int do_encb)
{
  const int blk = blockIdx.x;
  if (blk < 8192){
    int v = blk*256 + threadIdx.x;
    int flat = v*4; int j = flat >> 11; int k = flat & 2047;
    float4 f = *(const float4*)(Wih + flat);
    HL s0 = split1(f.x), s1 = split1(f.y), s2 = split1(f.z), s3 = split1(f.w);
    u16x4 h, l;
    h[0]=s0.h; h[1]=s1.h; h[2]=s2.h; h[3]=s3.h;
    l[0]=s0.l; l[1]=s1.l; l[2]=s2.l; l[3]=s3.l;
    if (k < 1024){
      *(u16x4*)(Wxh + (size_t)j*1024 + k) = h;
      *(u16x4*)(Wxl + (size_t)j*1024 + k) = l;
    } else {
      *(u16x4*)(Wrh + (size_t)j*2048 + (k-1024)) = h;
      *(u16x4*)(Wrl + (size_t)j*2048 + (k-1024)) = l;
    }
  } else if (blk < 12288){
    int v = (blk-8192)*256 + threadIdx.x;
    int flat = v*4; int j = flat >> 10; int k = flat & 1023;
    float4 f = *(const float4*)(Whh + flat);
    HL s0 = split1(f.x), s1 = split1(f.y), s2 = split1(f.z), s3 = split1(f.w);
    u16x4 h, l;
    h[0]=s0.h; h[1]=s1.h; h[2]=s2.h; h[3]=s3.h;
    l[0]=s0.l; l[1]=s1.l; l[2]=s2.l; l[3]=s3.l;
    *(u16x4*)(Wrh + (size_t)j*2048 + 1024 + k) = h;
    *(u16x4*)(Wrl + (size_t)j*2048 + 1024 + k) = l;
  } else if (blk < 14336){
    int v = (blk-12288)*256 + threadIdx.x;
    float4 f = *(const float4*)(Wout_f + (size_t)v*4);
    HL s0 = split1(f.x), s1 = split1(f.y), s2 = split1(f.z), s3 = split1(f.w);
    u16x4 h, l;
    h[0]=s0.h; h[1]=s1.h; h[2]=s2.h; h[3]=s3.h;
    l[0]=s0.l; l[1]=s1.l; l[2]=s2.l; l[3]=s3.l;
    *(u16x4*)(Woh + (size_t)v*4) = h;
    *(u16x4*)(Wol + (size_t)v*4) = l;
  } else if (blk < 15360){
    int v = (blk-14336)*256 + threadIdx.x;
    int flat = v*4; int m = flat >> 10; int k = flat & 1023;
    int t = m >> 5, b = m & 31;
    float4 f = *(const float4*)(inp + ((size_t)(b*32 + t) << 10) + k);
    HL s0 = split1(f.x), s1 = split1(f.y), s2 = split1(f.z), s3 = split1(f.w);
    u16x4 h, l;
    h[0]=s0.h; h[1]=s1.h; h[2]=s2.h; h[3]=s3.h;
    l[0]=s0.l; l[1]=s1.l; l[2]=s2.l; l[3]=s3.l;
    *(u16x4*)(Xh + flat) = h;
    *(u16x4*)(Xl + flat) = l;
  } else if (blk < 15795){
    int idx = (blk-15360)*256 + threadIdx.x;
    if (idx < 65536){
      int b = idx >> 11, col = idx & 2047;
      float v = (col < 1024) ? ha0[b*1024 + col] : h0[b*1024 + col - 1024];
      HL s = split1(v);
      Zh0[idx] = s.h; Zl0[idx] = s.l;
    } else if (idx < 65536 + 32768){
      int i = idx - 65536; cbuf[i] = c0[i];
    } else if (idx < 65536 + 32768 + 12800){
      int i = idx - 98304; out_past[i] = past[i];
    } else if (idx == 65536 + 32768 + 12800){
      out_loss[0] = 0.f;
    }
  } else {
    if (!do_encb) return;
    int v = (blk-15795)*256 + threadIdx.x;
    size_t flat = (size_t)v*8;
    int c = flat & 1023; int rem = flat >> 10;   // rem = s*32 + b
    int b = rem & 31, s = rem >> 5;
    float4 f0 = *(const float4*)(enc + flat);
    float4 f1 = *(const float4*)(enc + flat + 4);
    u16x4 h0v, h1v;
    h0v[0]=f2bf(f0.x); h0v[1]=f2bf(f0.y); h0v[2]=f2bf(f0.z); h0v[3]=f2bf(f0.w);
    h1v[0]=f2bf(f1.x); h1v[1]=f2bf(f1.y); h1v[2]=f2bf(f1.z); h1v[3]=f2bf(f1.w);
    u16* dst = encb + ((size_t)b*400 + s)*1024 + c;
    *(u16x4*)dst = h0v;
    *(u16x4*)(dst+4) = h1v;
  }
}

// W_attn [g][c] -> WaT [c][g] split hi/lo
__global__ __launch_bounds__(256) void watsplit_k(const float* __restrict__ Wattn,
    u16* __restrict__ Wth, u16* __restrict__ Wtl){
  __shared__ float t[32][33];
  int gx = blockIdx.x, cx = blockIdx.y;
  int ty = threadIdx.x >> 5, tx = threadIdx.x & 31;
  #pragma unroll
  for (int i=0;i<4;++i){
    int g = gx*32 + ty + i*8;
    t[ty+i*8][tx] = Wattn[(size_t)g*1024 + cx*32 + tx];
  }
  __syncthreads();
  #pragma unroll
  for (int i=0;i<4;++i){
    int c = cx*32 + ty + i*8;
    HL s = split1(t[tx][ty+i*8]);
    Wth[(size_t)c*1024 + gx*32 + tx] = s.h;
    Wtl[(size_t)c*1024 + gx*32 + tx] = s.l;
  }
}

// ---------------- 128x128 split-precision MFMA GEMM (x-path precompute) ----------------
__global__ __launch_bounds__(256) void gemm128_bias_k(
    const u16* __restrict__ Ah, const u16* __restrict__ Al,
    const u16* __restrict__ Bh, const u16* __restrict__ Bl, float* __restrict__ C,
    const float* __restrict__ bias0, const float* __restrict__ bias1, int M, int N, int K)
{
  __shared__ __align__(16) u16 Ash[4096], Asl[4096], Bsh[4096], Bsl[4096];
  const int tid = threadIdx.x;
  const int lane = tid & 63, w = tid >> 6;
  const int wm = w >> 1, wn = w & 1;
  const int m0 = blockIdx.y * 128, n0 = blockIdx.x * 128;
  const int r = lane & 15, q = lane >> 4;

  f32x4 acc[4][4];
  #pragma unroll
  for (int i=0;i<4;i++)
    #pragma unroll
    for (int j=0;j<4;j++) acc[i][j] = (f32x4){0.f,0.f,0.f,0.f};

  const int NT = K >> 5;
  const int srow = tid >> 2;
  const int skp  = (tid & 3) * 8;
  bf16x8 rah0, rah1, ral0, ral1, rbh0, rbh1, rbl0, rbl1;

  {
    size_t ao = (size_t)(m0 + srow) * K + skp;
    size_t bo = (size_t)(n0 + srow) * K + skp;
    rah0 = *(const bf16x8*)(Ah + ao);  rah1 = *(const bf16x8*)(Ah + ao + (size_t)64*K);
    ral0 = *(const bf16x8*)(Al + ao);  ral1 = *(const bf16x8*)(Al + ao + (size_t)64*K);
    rbh0 = *(const bf16x8*)(Bh + bo);  rbh1 = *(const bf16x8*)(Bh + bo + (size_t)64*K);
    rbl0 = *(const bf16x8*)(Bl + bo);  rbl1 = *(const bf16x8*)(Bl + bo + (size_t)64*K);
  }

  for (int kt = 0; kt < NT; ++kt){
    __syncthreads();
    *(bf16x8*)(Ash + tid*8)        = rah0;
    *(bf16x8*)(Ash + 2048 + tid*8) = rah1;
    *(bf16x8*)(Asl + tid*8)        = ral0;
    *(bf16x8*)(Asl + 2048 + tid*8) = ral1;
    *(bf16x8*)(Bsh + tid*8)        = rbh0;
    *(bf16x8*)(Bsh + 2048 + tid*8) = rbh1;
    *(bf16x8*)(Bsl + tid*8)        = rbl0;
    *(bf16x8*)(Bsl + 2048 + tid*8) = rbl1;
    __syncthreads();
    if (kt + 1 < NT){
      size_t ao = (size_t)(m0 + srow) * K + (kt+1)*32 + skp;
      size_t bo = (size_t)(n0 + srow) * K + (kt+1)*32 + skp;
      rah0 = *(const bf16x8*)(Ah + ao);  rah1 = *(const bf16x8*)(Ah + ao + (size_t)64*K);
      ral0 = *(const bf16x8*)(Al + ao);  ral1 = *(const bf16x8*)(Al + ao + (size_t)64*K);
      rbh0 = *(const bf16x8*)(Bh + bo);  rbh1 = *(const bf16x8*)(Bh + bo + (size_t)64*K);
      rbl0 = *(const bf16x8*)(Bl + bo);  rbl1 = *(const bf16x8*)(Bl + bo + (size_t)64*K);
    }
    bf16x8 afh[4], afl[4], bfh[4], bfl[4];
    #pragma unroll
    for (int mf=0; mf<4; ++mf){
      int off = (wm*64 + mf*16 + r)*32 + q*8;
      afh[mf] = *(const bf16x8*)(Ash + off);
      afl[mf] = *(const bf16x8*)(Asl + off);
    }
    #pragma unroll
    for (int nf=0; nf<4; ++nf){
      int off = (wn*64 + nf*16 + r)*32 + q*8;
      bfh[nf] = *(const bf16x8*)(Bsh + off);
      bfl[nf] = *(const bf16x8*)(Bsl + off);
    }
    #pragma unroll
    for (int mf=0; mf<4; ++mf)
      #pragma unroll
      for (int nf=0; nf<4; ++nf){
        acc[mf][nf] = mfma16(afh[mf], bfh[nf], acc[mf][nf]);
        acc[mf][nf] = mfma16(afh[mf], bfl[nf], acc[mf][nf]);
        acc[mf][nf] = mfma16(afl[mf], bfh[nf], acc[mf][nf]);
      }
  }

  #pragma unroll
  for (int mf=0; mf<4; ++mf)
    #pragma unroll
    for (int nf=0; nf<4; ++nf)
      #pragma unroll
      for (int rr=0; rr<4; ++rr){
        int row = m0 + wm*64 + mf*16 + q*4 + rr;
        int col = n0 + wn*64 + nf*16 + r;
        C[(size_t)row*N + col] = acc[mf][nf][rr] + bias0[col] + bias1[col];
      }
}

// ---------------- per-step kernels (5 dispatches, no cross-block sync) ----------------

// Fused recurrent GEMM + LSTM cell, single dispatch, full-K per block.
// 256 blocks: block j4 computes cols j4*4..+3 of ALL FOUR gates (16 MFMA cols),
// K=2048 split over 8 waves (256 each), LDS reduce, cell math in-block.
__global__ __launch_bounds__(512) void rec_cell_k(
    const u16* __restrict__ Zh, const u16* __restrict__ Zl,
    const u16* __restrict__ Wh, const u16* __restrict__ Wl,
    const float* __restrict__ gX, float* __restrict__ cbuf,
    u16* __restrict__ Znh, u16* __restrict__ Znl,
    u16* __restrict__ Zoh, u16* __restrict__ Zol,
    float* __restrict__ out_h, float* __restrict__ out_c, int last)
{
  __shared__ float red[8][512];
  __shared__ float gsum[512];
  const int tid = threadIdx.x, lane = tid & 63, w = tid >> 6;
  const int j4 = blockIdx.x;           // 0..255
  const int r = lane & 15, q = lane >> 4;
  const int k0 = w*256;

  f32x4 acc0 = (f32x4){0,0,0,0}, acc1 = (f32x4){0,0,0,0};
  const size_t aoff = (size_t)r*2048 + k0 + q*8;
  // B fragment row r -> Wrec row (r>>2)*1024 + j4*4 + (r&3)   (4 rows per gate)
  const size_t boff = (size_t)((r>>2)*1024 + j4*4 + (r&3))*2048 + k0 + q*8;
  #pragma unroll
  for (int kt = 0; kt < 8; ++kt){
    bf16x8 a0h = *(const bf16x8*)(Zh + aoff + kt*32);
    bf16x8 a0l = *(const bf16x8*)(Zl + aoff + kt*32);
    bf16x8 a1h = *(const bf16x8*)(Zh + aoff + (size_t)16*2048 + kt*32);
    bf16x8 a1l = *(const bf16x8*)(Zl + aoff + (size_t)16*2048 + kt*32);
    bf16x8 bh  = *(const bf16x8*)(Wh + boff + kt*32);
    bf16x8 bl  = *(const bf16x8*)(Wl + boff + kt*32);
    acc0 = mfma16(a0h, bh, acc0);
    acc0 = mfma16(a0h, bl, acc0);
    acc0 = mfma16(a0l, bh, acc0);
    acc1 = mfma16(a1h, bh, acc1);
    acc1 = mfma16(a1h, bl, acc1);
    acc1 = mfma16(a1l, bh, acc1);
  }
  #pragma unroll
  for (int rr=0; rr<4; ++rr){
    red[w][(q*4+rr)*16 + r]        = acc0[rr];   // b 0..15
    red[w][256 + (q*4+rr)*16 + r]  = acc1[rr];   // b 16..31
  }
  __syncthreads();
  {
    // gsum[b*16 + (g*4+c)] = full-K gate partial
    float v = 0.f;
    #pragma unroll
    for (int w2=0; w2<8; ++w2) v += red[w2][tid];
    gsum[tid] = v;
  }
  __syncthreads();
  if (tid < 128){
    int b = tid >> 2, c = tid & 3;
    int j = j4*4 + c;
    float gs[4];
    #pragma unroll
    for (int g=0; g<4; ++g)
      gs[g] = gsum[b*16 + g*4 + c] + gX[(size_t)b*4096 + g*1024 + j];
    int idx = b*1024 + j;
    float iv = 1.f/(1.f + expf(-gs[0]));
    float fv = 1.f/(1.f + expf(-gs[1]));
    float gv = tanhf(gs[2]);
    float ov = 1.f/(1.f + expf(-gs[3]));
    float cn = fv * cbuf[idx] + iv*gv;
    cbuf[idx] = cn;
    float h = ov * tanhf(cn);
    HL s = split1(h);
    size_t zi = (size_t)b*2048 + 1024 + j;
    Znh[zi] = s.h; Znl[zi] = s.l;
    Zoh[zi] = s.h; Zol[zi] = s.l;
    if (last){ out_h[idx] = h; out_c[idx] = cn; }
  }
}

// u[b,c] = sum_g h[b,g] * W_attn[g,c] via split MFMA vs transposed WaT.
__global__ __launch_bounds__(512) void u_mfma_k(
    const u16* __restrict__ Zoh, const u16* __restrict__ Zol,
    const u16* __restrict__ Wth, const u16* __restrict__ Wtl,
    float* __restrict__ ubuf)
{
  __shared__ float red[8][512];
  const int tid = threadIdx.x, lane = tid & 63, w = tid >> 6;
  const int cc = blockIdx.x;   // 0..63
  const int r = lane & 15, q = lane >> 4;
  f32x4 acc0 = (f32x4){0,0,0,0}, acc1 = (f32x4){0,0,0,0};
  const size_t aoff = (size_t)r*2048 + 1024 + w*128 + q*8;
  const size_t boff = (size_t)(cc*16 + r)*1024 + w*128 + q*8;
  #pragma unroll
  for (int kt=0; kt<4; ++kt){
    bf16x8 a0h = *(const bf16x8*)(Zoh + aoff + kt*32);
    bf16x8 a0l = *(const bf16x8*)(Zol + aoff + kt*32);
    bf16x8 a1h = *(const bf16x8*)(Zoh + aoff + (size_t)16*2048 + kt*32);
    bf16x8 a1l = *(const bf16x8*)(Zol + aoff + (size_t)16*2048 + kt*32);
    bf16x8 bh  = *(const bf16x8*)(Wth + boff + kt*32);
    bf16x8 bl  = *(const bf16x8*)(Wtl + boff + kt*32);
    acc0 = mfma16(a0h, bh, acc0);
    acc0 = mfma16(a0h, bl, acc0);
    acc0 = mfma16(a0l, bh, acc0);
    acc1 = mfma16(a1h, bh, acc1);
    acc1 = mfma16(a1h, bl, acc1);
    acc1 = mfma16(a1l, bh, acc1);
  }
  #pragma unroll
  for (int rr=0; rr<4; ++rr){
    red[w][(q*4+rr)*16 + r]      = acc0[rr];
    red[w][(16 + q*4+rr)*16 + r] = acc1[rr];
  }
  __syncthreads();
  {
    int b = tid >> 4, jj = tid & 15;
    float v = 0.f;
    #pragma unroll
    for (int w2=0; w2<8; ++w2) v += red[w2][tid];
    ubuf[(size_t)b*1024 + cc*16 + jj] = v;
  }
}

// Flash attention pass, bf16 enc: 512 blocks = (32 b x 16 s-chunks of 25).
__global__ __launch_bounds__(512) void flash_bf16_k(const u16* __restrict__ encb,
    const float* __restrict__ ubuf, float* __restrict__ scbuf,
    float* __restrict__ ctxp, float* __restrict__ mlbuf)
{
  __shared__ float wacc[8][1024];
  __shared__ float wml[16];
  const int tid = threadIdx.x, lane = tid & 63, w = tid >> 6;
  const int b = blockIdx.x >> 4, sc16 = blockIdx.x & 15;
  const int s0 = sc16 * 25;

  const float* up = ubuf + (size_t)b*1024 + lane*16;
  float uu[16];
  #pragma unroll
  for (int i=0;i<4;i++){ float4 t4 = *(const float4*)(up + i*4); uu[4*i]=t4.x; uu[4*i+1]=t4.y; uu[4*i+2]=t4.z; uu[4*i+3]=t4.w; }

  float m = -1e30f, l = 0.f;
  float acc[16];
  #pragma unroll
  for (int i=0;i<16;i++) acc[i] = 0.f;

  for (int s = s0 + w; s < s0 + 25; s += 8){
    const u16* ep = encb + ((size_t)b*400 + s)*1024 + lane*16;
    bf16x8 e0 = *(const bf16x8*)ep;
    bf16x8 e1 = *(const bf16x8*)(ep + 8);
    float er[16];
    #pragma unroll
    for (int i=0;i<8;i++){ er[i] = bf2f((u16)e0[i]); er[8+i] = bf2f((u16)e1[i]); }
    float sc = 0.f;
    #pragma unroll
    for (int i=0;i<16;i++) sc = fmaf(er[i], uu[i], sc);
    #pragma unroll
    for (int off=32; off; off>>=1) sc += __shfl_xor(sc, off);
    if (lane == 0) scbuf[(size_t)b*400 + s] = sc;
    if (sc > m){
      float f = expf(m - sc);
      l *= f;
      #pragma unroll
      for (int i=0;i<16;i++) acc[i] *= f;
      m = sc;
    }
    float wgt = expf(sc - m);
    l += wgt;
    #pragma unroll
    for (int i=0;i<16;i++) acc[i] = fmaf(wgt, er[i], acc[i]);
  }

  #pragma unroll
  for (int i=0;i<16;i++) wacc[w][lane*16+i] = acc[i];
  if (lane == 0){ wml[w*2] = m; wml[w*2+1] = l; }
  __syncthreads();

  float M = wml[0];
  #pragma unroll
  for (int i=1;i<8;i++) M = fmaxf(M, wml[i*2]);
  float c0v = 0.f, c1v = 0.f;
  #pragma unroll
  for (int i=0;i<8;i++){
    float f = expf(wml[i*2] - M);
    c0v = fmaf(wacc[i][tid],       f, c0v);
    c1v = fmaf(wacc[i][tid + 512], f, c1v);
  }
  size_t co = ((size_t)b*16 + sc16)*1024;
  ctxp[co + tid]       = c0v;
  ctxp[co + tid + 512] = c1v;
  if (tid == 0){
    float L = 0.f;
    #pragma unroll
    for (int i=0;i<8;i++) L += wml[i*2+1] * expf(wml[i*2] - M);
    mlbuf[((size_t)b*16 + sc16)*2]     = M;
    mlbuf[((size_t)b*16 + sc16)*2 + 1] = L;
  }
}

// Flash attention pass, f32 enc fallback (same chunking): 512 blocks.
__global__ __launch_bounds__(512) void flash_f32_k(const float* __restrict__ enc,
    const float* __restrict__ ubuf, float* __restrict__ scbuf,
    float* __restrict__ ctxp, float* __restrict__ mlbuf)
{
  __shared__ float wacc[8][1024];
  __shared__ float wml[16];
  const int tid = threadIdx.x, lane = tid & 63, w = tid >> 6;
  const int b = blockIdx.x >> 4, sc16 = blockIdx.x & 15;
  const int s0 = sc16 * 25;

  const float* up = ubuf + (size_t)b*1024 + lane*16;
  float uu[16];
  #pragma unroll
  for (int i=0;i<4;i++){ float4 t4 = *(const float4*)(up + i*4); uu[4*i]=t4.x; uu[4*i+1]=t4.y; uu[4*i+2]=t4.z; uu[4*i+3]=t4.w; }

  float m = -1e30f, l = 0.f;
  float acc[16];
  #pragma unroll
  for (int i=0;i<16;i++) acc[i] = 0.f;

  for (int s = s0 + w; s < s0 + 25; s += 8){
    const float* ep = enc + ((size_t)s*32 + b)*1024 + lane*16;
    float er[16];
    #pragma unroll
    for (int i=0;i<4;i++){ float4 e4 = *(const float4*)(ep + i*4); er[4*i]=e4.x; er[4*i+1]=e4.y; er[4*i+2]=e4.z; er[4*i+3]=e4.w; }
    float sc = 0.f;
    #pragma unroll
    for (int i=0;i<16;i++) sc = fmaf(er[i], uu[i], sc);
    #pragma unroll
    for (int off=32; off; off>>=1) sc += __shfl_xor(sc, off);
    if (lane == 0) scbuf[(size_t)b*400 + s] = sc;
    if (sc > m){
      float f = expf(m - sc);
      l *= f;
      #pragma unroll
      for (int i=0;i<16;i++) acc[i] *= f;
      m = sc;
    }
    float wgt = expf(sc - m);
    l += wgt;
    #pragma unroll
    for (int i=0;i<16;i++) acc[i] = fmaf(wgt, er[i], acc[i]);
  }

  #pragma unroll
  for (int i=0;i<16;i++) wacc[w][lane*16+i] = acc[i];
  if (lane == 0){ wml[w*2] = m; wml[w*2+1] = l; }
  __syncthreads();

  float M = wml[0];
  #pragma unroll
  for (int i=1;i<8;i++) M = fmaxf(M, wml[i*2]);
  float c0v = 0.f, c1v = 0.f;
  #pragma unroll
  for (int i=0;i<8;i++){
    float f = expf(wml[i*2] - M);
    c0v = fmaf(wacc[i][tid],       f, c0v);
    c1v = fmaf(wacc[i][tid + 512], f, c1v);
  }
  size_t co = ((size_t)b*16 + sc16)*1024;
  ctxp[co + tid]       = c0v;
  ctxp[co + tid + 512] = c1v;
  if (tid == 0){
    float L = 0.f;
    #pragma unroll
    for (int i=0;i<8;i++) L += wml[i*2+1] * expf(wml[i*2] - M);
    mlbuf[((size_t)b*16 + sc16)*2]     = M;
    mlbuf[((size_t)b*16 + sc16)*2 + 1] = L;
  }
}

// Combine 16 chunk partials: global (M,L), ctx -> Z split, attn output row.
__global__ __launch_bounds__(256) void combine_k(const float* __restrict__ scbuf,
    const float* __restrict__ ctxp, const float* __restrict__ mlbuf,
    u16* __restrict__ Zoh, u16* __restrict__ Zol, float* __restrict__ attn_out)
{
  const int b = blockIdx.x >> 3, cc = blockIdx.x & 7;
  const int tid = threadIdx.x;
  float M = -1e30f;
  #pragma unroll
  for (int i=0;i<16;i++) M = fmaxf(M, mlbuf[((size_t)b*16 + i)*2]);
  float L = 0.f;
  #pragma unroll
  for (int i=0;i<16;i++) L += mlbuf[((size_t)b*16 + i)*2 + 1] * expf(mlbuf[((size_t)b*16 + i)*2] - M);
  float invL = 1.f / L;
  if (tid < 128){
    int col = cc*128 + tid;
    float v = 0.f;
    #pragma unroll
    for (int i=0;i<16;i++)
      v = fmaf(ctxp[((size_t)b*16 + i)*1024 + col], expf(mlbuf[((size_t)b*16 + i)*2] - M), v);
    HL s = split1(v * invL);
    size_t zi = (size_t)b*2048 + col;
    Zoh[zi] = s.h; Zol[zi] = s.l;
  } else if (tid < 128 + 50){
    int s = cc*50 + (tid - 128);
    attn_out[(size_t)b*400 + s] = expf(scbuf[(size_t)b*400 + s] - M) * invL;
  }
}

// Fused full-K out-GEMM + tanh. Split-precision reduced to (a_h+a_l)*b_h:
// W_out-lo term dropped (error ~6e-4 absolute, no score-path amplification) -> no Wol reads.
// 128 blocks = (64 ub col-groups) x (2 bh row-halves); 8 waves K-split (256 each).
__global__ __launch_bounds__(512) void outg_fused_k(
    const u16* __restrict__ Zoh, const u16* __restrict__ Zol,
    const u16* __restrict__ Woh,
    float* __restrict__ out_outp /* + t*1024 */, u16* __restrict__ Znh, u16* __restrict__ Znl,
    float* __restrict__ out_hattn, int last)
{
  __shared__ float red[8][256];
  const int tid = threadIdx.x, lane = tid & 63, w = tid >> 6;
  const int ub = blockIdx.x & 63, bh = blockIdx.x >> 6;
  const int r = lane & 15, q = lane >> 4;
  const int k0 = w*256;
  f32x4 acc0 = (f32x4){0,0,0,0};
  const size_t aoff = (size_t)(bh*16 + r)*2048 + k0 + q*8;
  const size_t boff = (size_t)(ub*16 + r)*2048 + k0 + q*8;
  #pragma unroll
  for (int kt=0; kt<8; ++kt){
    bf16x8 ah = *(const bf16x8*)(Zoh + aoff + kt*32);
    bf16x8 al = *(const bf16x8*)(Zol + aoff + kt*32);
    bf16x8 bh_ = *(const bf16x8*)(Woh + boff + kt*32);
    acc0 = mfma16(ah, bh_, acc0);
    acc0 = mfma16(al, bh_, acc0);
  }
  #pragma unroll
  for (int rr=0; rr<4; ++rr)
    red[w][(q*4+rr)*16 + r] = acc0[rr];
  __syncthreads();
  if (tid < 256){
    int bloc = tid >> 4, jj = tid & 15;
    float z = 0.f;
    #pragma unroll
    for (int w2=0; w2<8; ++w2) z += red[w2][tid];
    int b = bh*16 + bloc;
    int u = ub*16 + jj;
    float ha = tanhf(z);
    out_outp[(size_t)b*32768 + u] = ha;
    HL s = split1(ha);
    Znh[(size_t)b*2048 + u] = s.h;
    Znl[(size_t)b*2048 + u] = s.l;
    if (last) out_hattn[(size_t)b*1024 + u] = ha;
  }
}

// ---------------- launch ----------------

extern "C" void kernel_launch(void* const* d_in, const int* in_sizes, int n_in,
                              void* d_out, int out_size, void* d_ws, size_t ws_size,
                              hipStream_t stream)
{
  const float* input_ = (const float*)d_in[0];
  const float* h0     = (const float*)d_in[1];
  const float* c0     = (const float*)d_in[2];
  const float* ha0    = (const float*)d_in[3];
  const float* enc    = (const float*)d_in[4];
  const float* past   = (const float*)d_in[5];
  const float* W_ih   = (const float*)d_in[6];
  const float* W_hh   = (const float*)d_in[7];
  const float* b_ih   = (const float*)d_in[8];
  const float* b_hh   = (const float*)d_in[9];
  const float* W_attn = (const float*)d_in[10];
  const float* W_out  = (const float*)d_in[11];
  float* out = (float*)d_out;

  // d_out layout (floats)
  const size_t OUT_OUTPUT = 0;            // [32][32][1024]
  const size_t OUT_H      = 1048576;
  const size_t OUT_C      = 1081344;
  const size_t OUT_HATTN  = 1114112;
  const size_t OUT_ATTN   = 1146880;      // [32][32][400]
  const size_t OUT_PAST   = 1556480;
  const size_t OUT_LOSS   = 1569280;

  // workspace layout (bytes)
  const size_t OFF_WRH   = 0;             // bf16 [4096][2048] hi
  const size_t OFF_WRL   = 16777216;
  const size_t OFF_WXH   = 33554432;      // bf16 [4096][1024]; after gateX: ctxp/ml scratch
  const size_t OFF_WXL   = 41943040;
  const size_t OFF_WOH   = 50331648;      // bf16 [1024][2048]
  const size_t OFF_WOL   = 54525952;
  const size_t OFF_XBH   = 58720256;      // bf16 [1024][1024]; after gateX: WaT hi
  const size_t OFF_XBL   = 60817408;      // after gateX: WaT lo
  const size_t OFF_GATEX = 62914560;      // f32 [32][32][4096]
  const size_t OFF_ZBH   = 79691776;      // bf16 [2][32][2048]
  const size_t OFF_ZBL   = 79953920;
  const size_t OFF_ZOH   = 80216064;      // bf16 [32][2048]
  const size_t OFF_ZOL   = 80347136;
  const size_t OFF_CBUF  = 80478208;      // f32 [32][1024]
  const size_t OFF_UBUF  = 80609280;      // f32 [32][1024]
  const size_t OFF_SC    = 80740352;      // f32 [32][400]
  const size_t WS_NEED   = 82939904;      // proven-OK base size
  if (ws_size < WS_NEED) return;  // fail loudly (poisoned output) rather than corrupt memory

  // enc-bf16 copy goes past the base if workspace allows
  const size_t OFF_ENCB  = WS_NEED;                 // bf16 [32][400][1024] = 26,214,400 B
  const size_t WS_BIG    = WS_NEED + 26214400;
  const bool use_bf16enc = (ws_size >= WS_BIG);

  // scratch aliases inside dead Wx region (dead after gemm128_bias_k)
  const size_t OFF_CTXP  = OFF_WXH;                 // f32 [32][16][1024] = 2 MB
  const size_t OFF_ML    = OFF_WXH + 2097152;       // f32 [32][16][2]

  char* ws = (char*)d_ws;
  u16*   Wrh   = (u16*)(ws + OFF_WRH);
  u16*   Wrl   = (u16*)(ws + OFF_WRL);
  u16*   Wxh   = (u16*)(ws + OFF_WXH);
  u16*   Wxl   = (u16*)(ws + OFF_WXL);
  u16*   Woh   = (u16*)(ws + OFF_WOH);
  u16*   Wol   = (u16*)(ws + OFF_WOL);
  u16*   Xbh   = (u16*)(ws + OFF_XBH);
  u16*   Xbl   = (u16*)(ws + OFF_XBL);
  u16*   Wth   = (u16*)(ws + OFF_XBH);   // alias: valid after gemm128_bias_k
  u16*   Wtl   = (u16*)(ws + OFF_XBL);
  float* gateX = (float*)(ws + OFF_GATEX);
  u16*   Zbh   = (u16*)(ws + OFF_ZBH);
  u16*   Zbl   = (u16*)(ws + OFF_ZBL);
  u16*   Zoh   = (u16*)(ws + OFF_ZOH);
  u16*   Zol   = (u16*)(ws + OFF_ZOL);
  float* cbuf  = (float*)(ws + OFF_CBUF);
  float* ubuf  = (float*)(ws + OFF_UBUF);
  float* sc    = (float*)(ws + OFF_SC);
  float* ctxp  = (float*)(ws + OFF_CTXP);
  float* mlbuf = (float*)(ws + OFF_ML);
  u16*   encb  = (u16*)(ws + OFF_ENCB);

  // ---- precompute (1 merged cast dispatch + GEMM + watsplit) ----
  cast_all_k<<<22195, 256, 0, stream>>>(W_ih, W_hh, W_out, input_,
      h0, c0, ha0, past, enc,
      Wxh, Wxl, Wrh, Wrl, Woh, Wol, Xbh, Xbl,
      Zbh, Zbl, cbuf, out + OUT_PAST, out + OUT_LOSS,
      encb, use_bf16enc ? 1 : 0);

  // gateX = Xb @ Wx^T + b_ih + b_hh   (M=1024, N=4096, K=1024)
  gemm128_bias_k<<<dim3(32, 8), 256, 0, stream>>>(Xbh, Xbl, Wxh, Wxl, gateX, b_ih, b_hh, 1024, 4096, 1024);
  // after gateX, Xb and Wx regions are dead -> WaT into Xb; ctxp/ml into Wx
  watsplit_k<<<dim3(32, 32), 256, 0, stream>>>(W_attn, Wth, Wtl);

  // ---- sequential decode: 5 dispatches per step, no cross-block sync ----
  for (int t = 0; t < 32; ++t){
    int p = t & 1;
    u16* Zih = Zbh + (size_t)p * 65536;
    u16* Zil = Zbl + (size_t)p * 65536;
    u16* Znh = Zbh + (size_t)(1-p) * 65536;
    u16* Znl = Zbl + (size_t)(1-p) * 65536;
    int last = (t == 31);
    rec_cell_k<<<256, 512, 0, stream>>>(Zih, Zil, Wrh, Wrl,
        gateX + (size_t)t*131072, cbuf, Znh, Znl, Zoh, Zol,
        out + OUT_H, out + OUT_C, last);
    u_mfma_k<<<64, 512, 0, stream>>>(Zoh, Zol, Wth, Wtl, ubuf);
    if (use_bf16enc)
      flash_bf16_k<<<512, 512, 0, stream>>>(encb, ubuf, sc, ctxp, mlbuf);
    else
      flash_f32_k<<<512, 512, 0, stream>>>(enc, ubuf, sc, ctxp, mlbuf);
    combine_k<<<256, 256, 0, stream>>>(sc, ctxp, mlbuf, Zoh, Zol,
        out + OUT_ATTN + (size_t)t*12800);
    outg_fused_k<<<128, 512, 0, stream>>>(Zoh, Zol, Woh,
        out + OUT_OUTPUT + (size_t)t*1024, Znh, Znl, out + OUT_HATTN, last);
  }
}